// Round 5
// baseline (1516.601 us; speedup 1.0000x reference)
//
#include <hip/hip_runtime.h>
#include <math.h>

// R4: occupancy + ILP round.
//  - LDS per wave 8KB -> 6.5KB (c1p unpadded rows [3][14][16], conv2 row-masking;
//    c3 overlays dead c1p) -> 6 blocks/CU.
//  - qsim runs 4 samples' rotation chains interleaved in registers (4-way ILP
//    on the serial shfl->fma chain), stashed from phase 1 via literal-indexed
//    per-sample register arrays.

#define WR_SZ 1664   // per-wave scratch floats (4 waves * 1664 * 4B = 26624 B/block)
#define NL   16384   // LUT entries

// Conjugated-rotation masks (verified absmax 0.0 in R2/R3).
constexpr int QM[7][8] = {
 {0x80,0x40,0x20,0x10,0x08,0x04,0x02,0x01},
 {0xC0,0x60,0x30,0x18,0x0C,0x06,0x03,0x01},
 {0xA0,0x50,0x28,0x14,0x0A,0x05,0x02,0x01},
 {0xF0,0x78,0x3C,0x1E,0x0F,0x07,0x03,0x01},
 {0x88,0x44,0x22,0x11,0x08,0x04,0x02,0x01},
 {0xCC,0x66,0x33,0x19,0x0C,0x06,0x03,0x01},
 {0xAA,0x55,0x2A,0x15,0x0A,0x05,0x02,0x01}};
constexpr int QR[7][8] = {
 {0x80,0x40,0x20,0x10,0x08,0x04,0x02,0x01},
 {0x80,0xC0,0xE0,0xF0,0xF8,0xFC,0xFE,0xFF},
 {0x80,0x40,0xA0,0x50,0xA8,0x54,0xAA,0x55},
 {0x80,0xC0,0x60,0x30,0x98,0xCC,0x66,0x33},
 {0x80,0x40,0x20,0x10,0x88,0x44,0x22,0x11},
 {0x80,0xC0,0xE0,0xF0,0x78,0x3C,0x1E,0x0F},
 {0x80,0x40,0xA0,0x50,0x28,0x14,0x0A,0x05}};

// One conjugated rotation applied to 4 interleaved sample-chains.
#define ROTSTEP4(L, Q) { \
    constexpr int m_  = QM[L][Q]; \
    constexpr int r_  = QR[L][Q]; \
    constexpr int lm_ = m_ >> 2, rm_ = m_ & 3; \
    constexpr int rl_ = r_ >> 2, rr_ = r_ & 3; \
    constexpr float f1_ = (rr_ & 1) ? -1.f : 1.f; \
    constexpr float f2_ = (rr_ & 2) ? -1.f : 1.f; \
    constexpr float f3_ = f1_ * f2_; \
    const float c_ = qtc[(L) * 8 + (Q)]; \
    const float s_ = qts[(L) * 8 + (Q)]; \
    float sgn_; \
    if constexpr (rl_ != 0) sgn_ = (__popc(lane & rl_) & 1) ? s_ : -s_; \
    else                    sgn_ = -s_; \
    float pA0_ = sA[0 ^ rm_], pA1_ = sA[1 ^ rm_], pA2_ = sA[2 ^ rm_], pA3_ = sA[3 ^ rm_]; \
    float pB0_ = sB[0 ^ rm_], pB1_ = sB[1 ^ rm_], pB2_ = sB[2 ^ rm_], pB3_ = sB[3 ^ rm_]; \
    float pC0_ = sC[0 ^ rm_], pC1_ = sC[1 ^ rm_], pC2_ = sC[2 ^ rm_], pC3_ = sC[3 ^ rm_]; \
    float pD0_ = sD[0 ^ rm_], pD1_ = sD[1 ^ rm_], pD2_ = sD[2 ^ rm_], pD3_ = sD[3 ^ rm_]; \
    if constexpr (lm_ != 0) { \
        pA0_ = __shfl_xor(pA0_, lm_); pA1_ = __shfl_xor(pA1_, lm_); \
        pA2_ = __shfl_xor(pA2_, lm_); pA3_ = __shfl_xor(pA3_, lm_); \
        pB0_ = __shfl_xor(pB0_, lm_); pB1_ = __shfl_xor(pB1_, lm_); \
        pB2_ = __shfl_xor(pB2_, lm_); pB3_ = __shfl_xor(pB3_, lm_); \
        pC0_ = __shfl_xor(pC0_, lm_); pC1_ = __shfl_xor(pC1_, lm_); \
        pC2_ = __shfl_xor(pC2_, lm_); pC3_ = __shfl_xor(pC3_, lm_); \
        pD0_ = __shfl_xor(pD0_, lm_); pD1_ = __shfl_xor(pD1_, lm_); \
        pD2_ = __shfl_xor(pD2_, lm_); pD3_ = __shfl_xor(pD3_, lm_); \
    } \
    sA[0] = fmaf(c_, sA[0], sgn_ * pA0_); \
    sA[1] = fmaf(c_, sA[1], (f1_ * sgn_) * pA1_); \
    sA[2] = fmaf(c_, sA[2], (f2_ * sgn_) * pA2_); \
    sA[3] = fmaf(c_, sA[3], (f3_ * sgn_) * pA3_); \
    sB[0] = fmaf(c_, sB[0], sgn_ * pB0_); \
    sB[1] = fmaf(c_, sB[1], (f1_ * sgn_) * pB1_); \
    sB[2] = fmaf(c_, sB[2], (f2_ * sgn_) * pB2_); \
    sB[3] = fmaf(c_, sB[3], (f3_ * sgn_) * pB3_); \
    sC[0] = fmaf(c_, sC[0], sgn_ * pC0_); \
    sC[1] = fmaf(c_, sC[1], (f1_ * sgn_) * pC1_); \
    sC[2] = fmaf(c_, sC[2], (f2_ * sgn_) * pC2_); \
    sC[3] = fmaf(c_, sC[3], (f3_ * sgn_) * pC3_); \
    sD[0] = fmaf(c_, sD[0], sgn_ * pD0_); \
    sD[1] = fmaf(c_, sD[1], (f1_ * sgn_) * pD1_); \
    sD[2] = fmaf(c_, sD[2], (f2_ * sgn_) * pD2_); \
    sD[3] = fmaf(c_, sD[3], (f3_ * sgn_) * pD3_); \
}

#define ROTLAYER4(L) \
    ROTSTEP4(L,0) ROTSTEP4(L,1) ROTSTEP4(L,2) ROTSTEP4(L,3) \
    ROTSTEP4(L,4) ROTSTEP4(L,5) ROTSTEP4(L,6) ROTSTEP4(L,7)

// ---------------- LUT builder: z(t) on a uniform grid over [-1,1], plus cos/sin ----------------
__global__ __launch_bounds__(256)
void build_lut(const float* __restrict__ w1, const float* __restrict__ b1,
               const float* __restrict__ w2, const float* __restrict__ b2,
               const float* __restrict__ w3, const float* __restrict__ b3,
               const float* __restrict__ w4, const float* __restrict__ b4,
               const float* __restrict__ w5, const float* __restrict__ b5,
               const float* __restrict__ qw,
               float* __restrict__ lut)
{
    __shared__ float hh[16][344];
    const int tid = threadIdx.x;
    const int e = tid >> 4;
    const int w = tid & 15;
    const int idx = blockIdx.x * 16 + e;
    const float t = -1.f + 2.f * (float)idx / (float)(NL - 1);

    if (blockIdx.x == 0 && tid < 56) {
        float th = 0.5f * qw[tid];
        lut[NL + tid]      = cosf(th);
        lut[NL + 56 + tid] = sinf(th);
    }

    float* hA = hh[e];
    float* hB = hA + 184;

    #pragma unroll
    for (int tt = 0; tt < 12; ++tt) {
        int j = tt * 16 + w;
        if (j < 180) hA[j] = fmaxf(fmaf(t, w1[j], b1[j]), 0.f);
    }
    for (int tt = 0; tt < 9; ++tt) {
        int j = tt * 16 + w;
        int jj = (j < 140) ? j : 0;
        const float4* wrow = (const float4*)(w2 + jj * 180);
        float a0 = 0.f, a1 = 0.f, a2 = 0.f, a3 = 0.f;
        for (int kc = 0; kc < 45; ++kc) {
            float4 h4 = *(const float4*)(hA + kc * 4);
            float4 ww = wrow[kc];
            a0 = fmaf(h4.x, ww.x, a0); a1 = fmaf(h4.y, ww.y, a1);
            a2 = fmaf(h4.z, ww.z, a2); a3 = fmaf(h4.w, ww.w, a3);
        }
        if (j < 140) hB[j] = fmaxf((a0 + a1) + (a2 + a3) + b2[j], 0.f);
    }
    for (int tt = 0; tt < 7; ++tt) {
        int j = tt * 16 + w;
        int jj = (j < 100) ? j : 0;
        const float4* wrow = (const float4*)(w3 + jj * 140);
        float a0 = 0.f, a1 = 0.f, a2 = 0.f, a3 = 0.f;
        for (int kc = 0; kc < 35; ++kc) {
            float4 h4 = *(const float4*)(hB + kc * 4);
            float4 ww = wrow[kc];
            a0 = fmaf(h4.x, ww.x, a0); a1 = fmaf(h4.y, ww.y, a1);
            a2 = fmaf(h4.z, ww.z, a2); a3 = fmaf(h4.w, ww.w, a3);
        }
        if (j < 100) hA[j] = fmaxf((a0 + a1) + (a2 + a3) + b3[j], 0.f);
    }
    for (int tt = 0; tt < 4; ++tt) {
        int j = tt * 16 + w;
        int jj = (j < 50) ? j : 0;
        const float4* wrow = (const float4*)(w4 + jj * 100);
        float a0 = 0.f, a1 = 0.f, a2 = 0.f, a3 = 0.f;
        for (int kc = 0; kc < 25; ++kc) {
            float4 h4 = *(const float4*)(hA + kc * 4);
            float4 ww = wrow[kc];
            a0 = fmaf(h4.x, ww.x, a0); a1 = fmaf(h4.y, ww.y, a1);
            a2 = fmaf(h4.z, ww.z, a2); a3 = fmaf(h4.w, ww.w, a3);
        }
        if (j < 50) hB[j] = fmaxf((a0 + a1) + (a2 + a3) + b4[j], 0.f);
    }
    float p5 = 0.f;
    for (int k = w; k < 50; k += 16) p5 = fmaf(hB[k], w5[k], p5);
    #pragma unroll
    for (int m = 1; m < 16; m <<= 1) p5 += __shfl_xor(p5, m);
    if (w == 0) lut[idx] = p5 + b5[0];
}

// ---------------- main fused kernel ----------------
__global__ __launch_bounds__(256, 6)
void fused_all(const float* __restrict__ x,
               const float* __restrict__ c1w, const float* __restrict__ c1b,
               const float* __restrict__ c2w, const float* __restrict__ c2b,
               const float* __restrict__ c3w, const float* __restrict__ c3b,
               const float* __restrict__ fcw, const float* __restrict__ fcb,
               const float* __restrict__ lut,
               float* __restrict__ out, int B)
{
    __shared__ float wreg[4][WR_SZ];

    const int tid  = threadIdx.x;
    const int lane = tid & 63;
    const int wv   = tid >> 6;

    const float* qtc = lut + NL;        // cos table (56), wave-uniform scalar reads
    const float* qts = lut + NL + 56;   // sin table

    float* wr = wreg[wv];
    const int base = blockIdx.x * 16;

    // per-sample stashed quantum states (literal-indexed -> registers)
    float sA[4], sB[4], sC[4], sD[4];

    // LDS layout per wave (floats):
    //   c1p : [0, 672)    = [3][14][16], col c stored at c+1 (cols 0,15 zero)
    //   pin : [672, 1664) = 31 rows x 32 cols input (pad 2) ; dead after conv1
    //   c2pT: [672, 1320) = [81 pos][8 ch] transposed conv2 out (reuses pin)
    //   c3  : [0, 588)    = 12*49 conv3 out (reuses dead c1p)
    //   pooled: [600, 648)
    float* c1p = wr;
    float* pin = wr + 672;
    float* c2pT = wr + 672;
    float* c3 = wr;
    float* pooled = wr + 600;

    for (int smp = 0; smp < 4; ++smp) {
        int sample = base + wv * 4 + smp;
        sample = (sample < B) ? sample : (B - 1);   // clamp (out store is guarded)

        // zero whole scratch [0,1664)
        {
            float4 z4 = {0.f, 0.f, 0.f, 0.f};
            #pragma unroll
            for (int t = 0; t < 6; ++t)
                *(float4*)(wr + t * 256 + lane * 4) = z4;
            if (lane < 32) *(float4*)(wr + 1536 + lane * 4) = z4;
        }
        {
            const float4* xs = (const float4*)(x + (size_t)sample * 784);
            #pragma unroll
            for (int t = 0; t < 4; ++t) {
                int i4 = t * 64 + lane;
                if (i4 < 196) {
                    float4 v = xs[i4];
                    int r = i4 / 7;
                    int c = (i4 % 7) * 4;
                    float* dst = pin + (r + 2) * 32 + (c + 2);
                    dst[0] = v.x; dst[1] = v.y; dst[2] = v.z; dst[3] = v.w;
                }
            }
        }

        // ---- conv1: 1x28x28 -> 3x14x14, k5 s2 p2 -> c1p [3][14][16] (col+1) ----
        #pragma unroll
        for (int t = 0; t < 4; ++t) {
            int p = t * 64 + lane;
            bool valid = p < 196;
            int pp = valid ? p : 0;
            int y = pp / 14, xx = pp % 14;
            const float* pr = pin + (2 * y) * 32 + 2 * xx;
            float win[25];
            #pragma unroll
            for (int ky = 0; ky < 5; ++ky) {
                const float* rw = pr + ky * 32;
                float2 a = *(const float2*)rw;
                float2 b = *(const float2*)(rw + 2);
                win[ky * 5 + 0] = a.x; win[ky * 5 + 1] = a.y;
                win[ky * 5 + 2] = b.x; win[ky * 5 + 3] = b.y;
                win[ky * 5 + 4] = rw[4];
            }
            #pragma unroll
            for (int c = 0; c < 3; ++c) {
                float acc = c1b[c];
                #pragma unroll
                for (int k = 0; k < 25; ++k)
                    acc = fmaf(win[k], c1w[c * 25 + k], acc);
                if (valid) c1p[c * 224 + y * 16 + (xx + 1)] = fmaxf(acc, 0.f);
            }
        }

        // ---- conv2: 3x14x14 -> 6x7x7 -> c2pT [81][8], k3 s2 p1 (row-masked) ----
        {
            // re-zero c2pT region [672,1320): 648 floats
            float4 z4 = {0.f, 0.f, 0.f, 0.f};
            #pragma unroll
            for (int t = 0; t < 2; ++t)
                *(float4*)(c2pT + t * 256 + lane * 4) = z4;
            if (lane < 34) *(float4*)(c2pT + 512 + lane * 4) = z4;
        }
        {
            int p = lane;
            bool valid = p < 49;
            int pp = valid ? p : 0;
            int y = pp / 7, xx = pp % 7;
            float acc[6];
            #pragma unroll
            for (int c = 0; c < 6; ++c) acc[c] = c2b[c];
            #pragma unroll
            for (int ic = 0; ic < 3; ++ic) {
                const float* bic = c1p + ic * 224;
                float win[9];
                #pragma unroll
                for (int ky = 0; ky < 3; ++ky) {
                    int rr = 2 * y - 1 + ky;           // [-1,13]; only -1 invalid
                    bool okr = rr >= 0;
                    int rc = okr ? rr : 0;
                    const float* rw = bic + rc * 16 + 2 * xx;  // cols 2xx..2xx+2 (stored +1 pad)
                    float2 a = *(const float2*)rw;
                    float e2 = rw[2];
                    win[ky * 3 + 0] = okr ? a.x : 0.f;
                    win[ky * 3 + 1] = okr ? a.y : 0.f;
                    win[ky * 3 + 2] = okr ? e2  : 0.f;
                }
                #pragma unroll
                for (int c = 0; c < 6; ++c)
                    #pragma unroll
                    for (int k = 0; k < 9; ++k)
                        acc[c] = fmaf(win[k], c2w[c * 27 + ic * 9 + k], acc[c]);
            }
            if (valid) {
                float* op = c2pT + ((y + 1) * 9 + (xx + 1)) * 8;
                float2 o01 = {fmaxf(acc[0], 0.f), fmaxf(acc[1], 0.f)};
                float2 o23 = {fmaxf(acc[2], 0.f), fmaxf(acc[3], 0.f)};
                float2 o45 = {fmaxf(acc[4], 0.f), fmaxf(acc[5], 0.f)};
                *(float2*)(op + 0) = o01;
                *(float2*)(op + 2) = o23;
                *(float2*)(op + 4) = o45;
            }
        }

        // ---- conv3: 6x7x7 -> 12x7x7 -> c3 (over dead c1p), k3 s1 p1 ----
        {
            int p = lane;
            bool valid = p < 49;
            int pp = valid ? p : 0;
            int y = pp / 7, xx = pp % 7;
            float acc[12];
            #pragma unroll
            for (int c = 0; c < 12; ++c) acc[c] = c3b[c];
            #pragma unroll
            for (int dy = 0; dy < 3; ++dy)
                #pragma unroll
                for (int dx = 0; dx < 3; ++dx) {
                    const float* cp = c2pT + ((y + dy) * 9 + (xx + dx)) * 8;
                    float4 ch03 = *(const float4*)cp;
                    float2 ch45 = *(const float2*)(cp + 4);
                    const int k = dy * 3 + dx;
                    #pragma unroll
                    for (int c = 0; c < 12; ++c) {
                        const float* wp = c3w + c * 54 + k;
                        acc[c] = fmaf(ch03.x, wp[0],  acc[c]);
                        acc[c] = fmaf(ch03.y, wp[9],  acc[c]);
                        acc[c] = fmaf(ch03.z, wp[18], acc[c]);
                        acc[c] = fmaf(ch03.w, wp[27], acc[c]);
                        acc[c] = fmaf(ch45.x, wp[36], acc[c]);
                        acc[c] = fmaf(ch45.y, wp[45], acc[c]);
                    }
                }
            if (valid) {
                #pragma unroll
                for (int c = 0; c < 12; ++c)
                    c3[c * 49 + p] = fmaxf(acc[c], 0.f);
            }
        }

        // ---- adaptive pool (overlapping 4x4 bins) -> pooled[0..48) ----
        {
            int o = lane;
            if (o < 48) {
                int c = o >> 2, i = (o >> 1) & 1, j = o & 1;
                int ri = i * 3, cj = j * 3;
                float s = 0.f;
                #pragma unroll
                for (int dy = 0; dy < 4; ++dy)
                    #pragma unroll
                    for (int dx = 0; dx < 4; ++dx)
                        s += c3[c * 49 + (ri + dy) * 7 + (cj + dx)];
                pooled[o] = s * (1.f / 16.f);
            }
        }

        // ---- fc 48->256 + relu + L2-normalize; lane l keeps feats 4l..4l+3 ----
        float st[4];
        {
            const int o0 = lane * 4;
            const float4* wr0 = (const float4*)(fcw + (o0 + 0) * 48);
            const float4* wr1 = (const float4*)(fcw + (o0 + 1) * 48);
            const float4* wr2 = (const float4*)(fcw + (o0 + 2) * 48);
            const float4* wr3 = (const float4*)(fcw + (o0 + 3) * 48);
            float a0 = 0.f, a1 = 0.f, a2 = 0.f, a3 = 0.f;
            #pragma unroll
            for (int kc = 0; kc < 12; ++kc) {
                float4 pv = *(const float4*)(pooled + kc * 4);
                float4 q0 = wr0[kc], q1 = wr1[kc], q2 = wr2[kc], q3 = wr3[kc];
                a0 = fmaf(pv.x, q0.x, a0); a0 = fmaf(pv.y, q0.y, a0);
                a0 = fmaf(pv.z, q0.z, a0); a0 = fmaf(pv.w, q0.w, a0);
                a1 = fmaf(pv.x, q1.x, a1); a1 = fmaf(pv.y, q1.y, a1);
                a1 = fmaf(pv.z, q1.z, a1); a1 = fmaf(pv.w, q1.w, a1);
                a2 = fmaf(pv.x, q2.x, a2); a2 = fmaf(pv.y, q2.y, a2);
                a2 = fmaf(pv.z, q2.z, a2); a2 = fmaf(pv.w, q2.w, a2);
                a3 = fmaf(pv.x, q3.x, a3); a3 = fmaf(pv.y, q3.y, a3);
                a3 = fmaf(pv.z, q3.z, a3); a3 = fmaf(pv.w, q3.w, a3);
            }
            float4 fb = *(const float4*)(fcb + o0);
            float v0 = fmaxf(a0 + fb.x, 0.f);
            float v1 = fmaxf(a1 + fb.y, 0.f);
            float v2 = fmaxf(a2 + fb.z, 0.f);
            float v3 = fmaxf(a3 + fb.w, 0.f);
            float ss = v0 * v0 + v1 * v1 + v2 * v2 + v3 * v3;
            #pragma unroll
            for (int m = 1; m < 64; m <<= 1) ss += __shfl_xor(ss, m);
            float scale = 1.f / fmaxf(sqrtf(ss), 1e-12f);
            st[0] = v0 * scale; st[1] = v1 * scale;
            st[2] = v2 * scale; st[3] = v3 * scale;
        }

        // stash into per-sample register chains (uniform branch on loop counter)
        if (smp == 0)      { sA[0]=st[0]; sA[1]=st[1]; sA[2]=st[2]; sA[3]=st[3]; }
        else if (smp == 1) { sB[0]=st[0]; sB[1]=st[1]; sB[2]=st[2]; sB[3]=st[3]; }
        else if (smp == 2) { sC[0]=st[0]; sC[1]=st[1]; sC[2]=st[2]; sC[3]=st[3]; }
        else               { sD[0]=st[0]; sD[1]=st[1]; sD[2]=st[2]; sD[3]=st[3]; }
    }

    // ---- qsim: 56 conjugated rotations on 4 interleaved chains ----
    ROTLAYER4(0) ROTLAYER4(1) ROTLAYER4(2) ROTLAYER4(3)
    ROTLAYER4(4) ROTLAYER4(5) ROTLAYER4(6)

    // ---- measurement per sample: bit7 = lane bit5 ----
    float pA = sA[0]*sA[0] + sA[1]*sA[1] + sA[2]*sA[2] + sA[3]*sA[3];
    float pB = sB[0]*sB[0] + sB[1]*sB[1] + sB[2]*sB[2] + sB[3]*sB[3];
    float pC = sC[0]*sC[0] + sC[1]*sC[1] + sC[2]*sC[2] + sC[3]*sC[3];
    float pD = sD[0]*sD[0] + sD[1]*sD[1] + sD[2]*sD[2] + sD[3]*sD[3];
    if (lane & 32) { pA = -pA; pB = -pB; pC = -pC; pD = -pD; }
    #pragma unroll
    for (int m = 1; m < 64; m <<= 1) {
        pA += __shfl_xor(pA, m); pB += __shfl_xor(pB, m);
        pC += __shfl_xor(pC, m); pD += __shfl_xor(pD, m);
    }

    if (lane < 4) {
        float qout = (lane == 0) ? pA : (lane == 1) ? pB : (lane == 2) ? pC : pD;
        int osample = base + wv * 4 + lane;
        float u = (qout + 1.f) * 0.5f * (float)(NL - 1);
        int i0 = (int)floorf(u);
        i0 = (i0 < 0) ? 0 : ((i0 > NL - 2) ? NL - 2 : i0);
        float fr = u - (float)i0;
        float z0 = lut[i0], z1 = lut[i0 + 1];
        float z = fmaf(z1 - z0, fr, z0);
        if (osample < B) out[osample] = 1.f / (1.f + expf(-z));
    }
}

extern "C" void kernel_launch(void* const* d_in, const int* in_sizes, int n_in,
                              void* d_out, int out_size, void* d_ws, size_t ws_size,
                              hipStream_t stream) {
    const float* x   = (const float*)d_in[0];
    const float* c1w = (const float*)d_in[1];
    const float* c1b = (const float*)d_in[2];
    const float* c2w = (const float*)d_in[3];
    const float* c2b = (const float*)d_in[4];
    const float* c3w = (const float*)d_in[5];
    const float* c3b = (const float*)d_in[6];
    const float* fcw = (const float*)d_in[7];
    const float* fcb = (const float*)d_in[8];
    const float* qw  = (const float*)d_in[9];
    const float* w1  = (const float*)d_in[10];
    const float* b1  = (const float*)d_in[11];
    const float* w2  = (const float*)d_in[12];
    const float* b2  = (const float*)d_in[13];
    const float* w3  = (const float*)d_in[14];
    const float* b3  = (const float*)d_in[15];
    const float* w4  = (const float*)d_in[16];
    const float* b4  = (const float*)d_in[17];
    const float* w5  = (const float*)d_in[18];
    const float* b5  = (const float*)d_in[19];

    float* lut = (float*)d_ws;   // NL z-values + 112 cos/sin

    build_lut<<<dim3(NL / 16), dim3(256), 0, stream>>>(
        w1, b1, w2, b2, w3, b3, w4, b4, w5, b5, qw, lut);

    int B = in_sizes[0] / 784;
    int grid = (B + 15) / 16;
    fused_all<<<dim3(grid), dim3(256), 0, stream>>>(
        x, c1w, c1b, c2w, c2b, c3w, c3b, fcw, fcb, lut,
        (float*)d_out, B);
}

// Round 6
// 685.352 us; speedup vs baseline: 2.2129x; 2.2129x over previous
//
#include <hip/hip_runtime.h>
#include <math.h>

// R5: two-kernel split.
//  A) conv1/conv2/conv3/pool -> pooled[48] per sample in d_ws (R4's validated
//     conv LDS layout; 26.6KB/block -> 6 blocks/CU; no qsim register pressure).
//  B) fc48->256 + L2-normalize + 4-way-interleaved conjugated qsim + LUT
//     classifier. Zero LDS, fcw loads amortized over 4 samples/wave.

#define WR_SZ 1664   // per-wave conv scratch floats (4 waves * 1664 * 4B = 26624 B/block)
#define NL   16384   // LUT entries
#define POOL_OFF (NL + 128)   // float offset of pooled buffer in d_ws

// Conjugated-rotation masks (verified absmax 0.0 in R2/R3/R4).
constexpr int QM[7][8] = {
 {0x80,0x40,0x20,0x10,0x08,0x04,0x02,0x01},
 {0xC0,0x60,0x30,0x18,0x0C,0x06,0x03,0x01},
 {0xA0,0x50,0x28,0x14,0x0A,0x05,0x02,0x01},
 {0xF0,0x78,0x3C,0x1E,0x0F,0x07,0x03,0x01},
 {0x88,0x44,0x22,0x11,0x08,0x04,0x02,0x01},
 {0xCC,0x66,0x33,0x19,0x0C,0x06,0x03,0x01},
 {0xAA,0x55,0x2A,0x15,0x0A,0x05,0x02,0x01}};
constexpr int QR[7][8] = {
 {0x80,0x40,0x20,0x10,0x08,0x04,0x02,0x01},
 {0x80,0xC0,0xE0,0xF0,0xF8,0xFC,0xFE,0xFF},
 {0x80,0x40,0xA0,0x50,0xA8,0x54,0xAA,0x55},
 {0x80,0xC0,0x60,0x30,0x98,0xCC,0x66,0x33},
 {0x80,0x40,0x20,0x10,0x88,0x44,0x22,0x11},
 {0x80,0xC0,0xE0,0xF0,0x78,0x3C,0x1E,0x0F},
 {0x80,0x40,0xA0,0x50,0x28,0x14,0x0A,0x05}};

// One conjugated rotation applied to 4 interleaved sample-chains.
#define ROTSTEP4(L, Q) { \
    constexpr int m_  = QM[L][Q]; \
    constexpr int r_  = QR[L][Q]; \
    constexpr int lm_ = m_ >> 2, rm_ = m_ & 3; \
    constexpr int rl_ = r_ >> 2, rr_ = r_ & 3; \
    constexpr float f1_ = (rr_ & 1) ? -1.f : 1.f; \
    constexpr float f2_ = (rr_ & 2) ? -1.f : 1.f; \
    constexpr float f3_ = f1_ * f2_; \
    const float c_ = qtc[(L) * 8 + (Q)]; \
    const float s_ = qts[(L) * 8 + (Q)]; \
    float sgn_; \
    if constexpr (rl_ != 0) sgn_ = (__popc(lane & rl_) & 1) ? s_ : -s_; \
    else                    sgn_ = -s_; \
    float pA0_ = sA[0 ^ rm_], pA1_ = sA[1 ^ rm_], pA2_ = sA[2 ^ rm_], pA3_ = sA[3 ^ rm_]; \
    float pB0_ = sB[0 ^ rm_], pB1_ = sB[1 ^ rm_], pB2_ = sB[2 ^ rm_], pB3_ = sB[3 ^ rm_]; \
    float pC0_ = sC[0 ^ rm_], pC1_ = sC[1 ^ rm_], pC2_ = sC[2 ^ rm_], pC3_ = sC[3 ^ rm_]; \
    float pD0_ = sD[0 ^ rm_], pD1_ = sD[1 ^ rm_], pD2_ = sD[2 ^ rm_], pD3_ = sD[3 ^ rm_]; \
    if constexpr (lm_ != 0) { \
        pA0_ = __shfl_xor(pA0_, lm_); pA1_ = __shfl_xor(pA1_, lm_); \
        pA2_ = __shfl_xor(pA2_, lm_); pA3_ = __shfl_xor(pA3_, lm_); \
        pB0_ = __shfl_xor(pB0_, lm_); pB1_ = __shfl_xor(pB1_, lm_); \
        pB2_ = __shfl_xor(pB2_, lm_); pB3_ = __shfl_xor(pB3_, lm_); \
        pC0_ = __shfl_xor(pC0_, lm_); pC1_ = __shfl_xor(pC1_, lm_); \
        pC2_ = __shfl_xor(pC2_, lm_); pC3_ = __shfl_xor(pC3_, lm_); \
        pD0_ = __shfl_xor(pD0_, lm_); pD1_ = __shfl_xor(pD1_, lm_); \
        pD2_ = __shfl_xor(pD2_, lm_); pD3_ = __shfl_xor(pD3_, lm_); \
    } \
    sA[0] = fmaf(c_, sA[0], sgn_ * pA0_); \
    sA[1] = fmaf(c_, sA[1], (f1_ * sgn_) * pA1_); \
    sA[2] = fmaf(c_, sA[2], (f2_ * sgn_) * pA2_); \
    sA[3] = fmaf(c_, sA[3], (f3_ * sgn_) * pA3_); \
    sB[0] = fmaf(c_, sB[0], sgn_ * pB0_); \
    sB[1] = fmaf(c_, sB[1], (f1_ * sgn_) * pB1_); \
    sB[2] = fmaf(c_, sB[2], (f2_ * sgn_) * pB2_); \
    sB[3] = fmaf(c_, sB[3], (f3_ * sgn_) * pB3_); \
    sC[0] = fmaf(c_, sC[0], sgn_ * pC0_); \
    sC[1] = fmaf(c_, sC[1], (f1_ * sgn_) * pC1_); \
    sC[2] = fmaf(c_, sC[2], (f2_ * sgn_) * pC2_); \
    sC[3] = fmaf(c_, sC[3], (f3_ * sgn_) * pC3_); \
    sD[0] = fmaf(c_, sD[0], sgn_ * pD0_); \
    sD[1] = fmaf(c_, sD[1], (f1_ * sgn_) * pD1_); \
    sD[2] = fmaf(c_, sD[2], (f2_ * sgn_) * pD2_); \
    sD[3] = fmaf(c_, sD[3], (f3_ * sgn_) * pD3_); \
}

#define ROTLAYER4(L) \
    ROTSTEP4(L,0) ROTSTEP4(L,1) ROTSTEP4(L,2) ROTSTEP4(L,3) \
    ROTSTEP4(L,4) ROTSTEP4(L,5) ROTSTEP4(L,6) ROTSTEP4(L,7)

// ---------------- LUT builder: z(t) on a uniform grid over [-1,1], plus cos/sin ----------------
__global__ __launch_bounds__(256)
void build_lut(const float* __restrict__ w1, const float* __restrict__ b1,
               const float* __restrict__ w2, const float* __restrict__ b2,
               const float* __restrict__ w3, const float* __restrict__ b3,
               const float* __restrict__ w4, const float* __restrict__ b4,
               const float* __restrict__ w5, const float* __restrict__ b5,
               const float* __restrict__ qw,
               float* __restrict__ lut)
{
    __shared__ float hh[16][344];
    const int tid = threadIdx.x;
    const int e = tid >> 4;
    const int w = tid & 15;
    const int idx = blockIdx.x * 16 + e;
    const float t = -1.f + 2.f * (float)idx / (float)(NL - 1);

    if (blockIdx.x == 0 && tid < 56) {
        float th = 0.5f * qw[tid];
        lut[NL + tid]      = cosf(th);
        lut[NL + 56 + tid] = sinf(th);
    }

    float* hA = hh[e];
    float* hB = hA + 184;

    #pragma unroll
    for (int tt = 0; tt < 12; ++tt) {
        int j = tt * 16 + w;
        if (j < 180) hA[j] = fmaxf(fmaf(t, w1[j], b1[j]), 0.f);
    }
    for (int tt = 0; tt < 9; ++tt) {
        int j = tt * 16 + w;
        int jj = (j < 140) ? j : 0;
        const float4* wrow = (const float4*)(w2 + jj * 180);
        float a0 = 0.f, a1 = 0.f, a2 = 0.f, a3 = 0.f;
        for (int kc = 0; kc < 45; ++kc) {
            float4 h4 = *(const float4*)(hA + kc * 4);
            float4 ww = wrow[kc];
            a0 = fmaf(h4.x, ww.x, a0); a1 = fmaf(h4.y, ww.y, a1);
            a2 = fmaf(h4.z, ww.z, a2); a3 = fmaf(h4.w, ww.w, a3);
        }
        if (j < 140) hB[j] = fmaxf((a0 + a1) + (a2 + a3) + b2[j], 0.f);
    }
    for (int tt = 0; tt < 7; ++tt) {
        int j = tt * 16 + w;
        int jj = (j < 100) ? j : 0;
        const float4* wrow = (const float4*)(w3 + jj * 140);
        float a0 = 0.f, a1 = 0.f, a2 = 0.f, a3 = 0.f;
        for (int kc = 0; kc < 35; ++kc) {
            float4 h4 = *(const float4*)(hB + kc * 4);
            float4 ww = wrow[kc];
            a0 = fmaf(h4.x, ww.x, a0); a1 = fmaf(h4.y, ww.y, a1);
            a2 = fmaf(h4.z, ww.z, a2); a3 = fmaf(h4.w, ww.w, a3);
        }
        if (j < 100) hA[j] = fmaxf((a0 + a1) + (a2 + a3) + b3[j], 0.f);
    }
    for (int tt = 0; tt < 4; ++tt) {
        int j = tt * 16 + w;
        int jj = (j < 50) ? j : 0;
        const float4* wrow = (const float4*)(w4 + jj * 100);
        float a0 = 0.f, a1 = 0.f, a2 = 0.f, a3 = 0.f;
        for (int kc = 0; kc < 25; ++kc) {
            float4 h4 = *(const float4*)(hA + kc * 4);
            float4 ww = wrow[kc];
            a0 = fmaf(h4.x, ww.x, a0); a1 = fmaf(h4.y, ww.y, a1);
            a2 = fmaf(h4.z, ww.z, a2); a3 = fmaf(h4.w, ww.w, a3);
        }
        if (j < 50) hB[j] = fmaxf((a0 + a1) + (a2 + a3) + b4[j], 0.f);
    }
    float p5 = 0.f;
    for (int k = w; k < 50; k += 16) p5 = fmaf(hB[k], w5[k], p5);
    #pragma unroll
    for (int m = 1; m < 16; m <<= 1) p5 += __shfl_xor(p5, m);
    if (w == 0) lut[idx] = p5 + b5[0];
}

// ---------------- kernel A: convs + pool -> pooled[48]/sample ----------------
__global__ __launch_bounds__(256, 6)
void conv_pool(const float* __restrict__ x,
               const float* __restrict__ c1w, const float* __restrict__ c1b,
               const float* __restrict__ c2w, const float* __restrict__ c2b,
               const float* __restrict__ c3w, const float* __restrict__ c3b,
               float* __restrict__ poolg, int B)
{
    __shared__ float wreg[4][WR_SZ];

    const int tid  = threadIdx.x;
    const int lane = tid & 63;
    const int wv   = tid >> 6;

    float* wr = wreg[wv];
    const int base = blockIdx.x * 16;

    // LDS layout per wave (floats):
    //   c1p : [0, 672)    = [3][14][16], col c at c+1 (cols 0,15 zero)
    //   pin : [672, 1664) = 31 rows x 32 cols input (pad 2); dead after conv1
    //   c2pT: [672, 1320) = [81 pos][8 ch] transposed conv2 out (reuses pin)
    //   c3  : [0, 588)    = 12*49 conv3 out (reuses dead c1p)
    float* c1p  = wr;
    float* pin  = wr + 672;
    float* c2pT = wr + 672;
    float* c3   = wr;

    for (int smp = 0; smp < 4; ++smp) {
        const int sample = base + wv * 4 + smp;
        if (sample >= B) break;

        // zero whole scratch [0,1664)
        {
            float4 z4 = {0.f, 0.f, 0.f, 0.f};
            #pragma unroll
            for (int t = 0; t < 6; ++t)
                *(float4*)(wr + t * 256 + lane * 4) = z4;
            if (lane < 32) *(float4*)(wr + 1536 + lane * 4) = z4;
        }
        {
            const float4* xs = (const float4*)(x + (size_t)sample * 784);
            #pragma unroll
            for (int t = 0; t < 4; ++t) {
                int i4 = t * 64 + lane;
                if (i4 < 196) {
                    float4 v = xs[i4];
                    int r = i4 / 7;
                    int c = (i4 % 7) * 4;
                    float* dst = pin + (r + 2) * 32 + (c + 2);
                    dst[0] = v.x; dst[1] = v.y; dst[2] = v.z; dst[3] = v.w;
                }
            }
        }

        // ---- conv1: 1x28x28 -> 3x14x14, k5 s2 p2 -> c1p [3][14][16] (col+1) ----
        #pragma unroll
        for (int t = 0; t < 4; ++t) {
            int p = t * 64 + lane;
            bool valid = p < 196;
            int pp = valid ? p : 0;
            int y = pp / 14, xx = pp % 14;
            const float* pr = pin + (2 * y) * 32 + 2 * xx;
            float win[25];
            #pragma unroll
            for (int ky = 0; ky < 5; ++ky) {
                const float* rw = pr + ky * 32;
                float2 a = *(const float2*)rw;
                float2 b = *(const float2*)(rw + 2);
                win[ky * 5 + 0] = a.x; win[ky * 5 + 1] = a.y;
                win[ky * 5 + 2] = b.x; win[ky * 5 + 3] = b.y;
                win[ky * 5 + 4] = rw[4];
            }
            #pragma unroll
            for (int c = 0; c < 3; ++c) {
                float acc = c1b[c];
                #pragma unroll
                for (int k = 0; k < 25; ++k)
                    acc = fmaf(win[k], c1w[c * 25 + k], acc);
                if (valid) c1p[c * 224 + y * 16 + (xx + 1)] = fmaxf(acc, 0.f);
            }
        }

        // ---- conv2: 3x14x14 -> 6x7x7 -> c2pT [81][8], k3 s2 p1 (row-masked) ----
        {
            float4 z4 = {0.f, 0.f, 0.f, 0.f};
            #pragma unroll
            for (int t = 0; t < 2; ++t)
                *(float4*)(c2pT + t * 256 + lane * 4) = z4;
            if (lane < 34) *(float4*)(c2pT + 512 + lane * 4) = z4;
        }
        {
            int p = lane;
            bool valid = p < 49;
            int pp = valid ? p : 0;
            int y = pp / 7, xx = pp % 7;
            float acc[6];
            #pragma unroll
            for (int c = 0; c < 6; ++c) acc[c] = c2b[c];
            #pragma unroll
            for (int ic = 0; ic < 3; ++ic) {
                const float* bic = c1p + ic * 224;
                float win[9];
                #pragma unroll
                for (int ky = 0; ky < 3; ++ky) {
                    int rr = 2 * y - 1 + ky;           // [-1,13]; only -1 invalid
                    bool okr = rr >= 0;
                    int rc = okr ? rr : 0;
                    const float* rw = bic + rc * 16 + 2 * xx;
                    float2 a = *(const float2*)rw;
                    float e2 = rw[2];
                    win[ky * 3 + 0] = okr ? a.x : 0.f;
                    win[ky * 3 + 1] = okr ? a.y : 0.f;
                    win[ky * 3 + 2] = okr ? e2  : 0.f;
                }
                #pragma unroll
                for (int c = 0; c < 6; ++c)
                    #pragma unroll
                    for (int k = 0; k < 9; ++k)
                        acc[c] = fmaf(win[k], c2w[c * 27 + ic * 9 + k], acc[c]);
            }
            if (valid) {
                float* op = c2pT + ((y + 1) * 9 + (xx + 1)) * 8;
                float2 o01 = {fmaxf(acc[0], 0.f), fmaxf(acc[1], 0.f)};
                float2 o23 = {fmaxf(acc[2], 0.f), fmaxf(acc[3], 0.f)};
                float2 o45 = {fmaxf(acc[4], 0.f), fmaxf(acc[5], 0.f)};
                *(float2*)(op + 0) = o01;
                *(float2*)(op + 2) = o23;
                *(float2*)(op + 4) = o45;
            }
        }

        // ---- conv3: 6x7x7 -> 12x7x7 -> c3 (over dead c1p), k3 s1 p1 ----
        {
            int p = lane;
            bool valid = p < 49;
            int pp = valid ? p : 0;
            int y = pp / 7, xx = pp % 7;
            float acc[12];
            #pragma unroll
            for (int c = 0; c < 12; ++c) acc[c] = c3b[c];
            #pragma unroll
            for (int dy = 0; dy < 3; ++dy)
                #pragma unroll
                for (int dx = 0; dx < 3; ++dx) {
                    const float* cp = c2pT + ((y + dy) * 9 + (xx + dx)) * 8;
                    float4 ch03 = *(const float4*)cp;
                    float2 ch45 = *(const float2*)(cp + 4);
                    const int k = dy * 3 + dx;
                    #pragma unroll
                    for (int c = 0; c < 12; ++c) {
                        const float* wp = c3w + c * 54 + k;
                        acc[c] = fmaf(ch03.x, wp[0],  acc[c]);
                        acc[c] = fmaf(ch03.y, wp[9],  acc[c]);
                        acc[c] = fmaf(ch03.z, wp[18], acc[c]);
                        acc[c] = fmaf(ch03.w, wp[27], acc[c]);
                        acc[c] = fmaf(ch45.x, wp[36], acc[c]);
                        acc[c] = fmaf(ch45.y, wp[45], acc[c]);
                    }
                }
            if (valid) {
                #pragma unroll
                for (int c = 0; c < 12; ++c)
                    c3[c * 49 + p] = fmaxf(acc[c], 0.f);
            }
        }

        // ---- adaptive pool -> write pooled[48] straight to global ----
        {
            int o = lane;
            if (o < 48) {
                int c = o >> 2, i = (o >> 1) & 1, j = o & 1;
                int ri = i * 3, cj = j * 3;
                float s = 0.f;
                #pragma unroll
                for (int dy = 0; dy < 4; ++dy)
                    #pragma unroll
                    for (int dx = 0; dx < 4; ++dx)
                        s += c3[c * 49 + (ri + dy) * 7 + (cj + dx)];
                poolg[(size_t)sample * 48 + o] = s * (1.f / 16.f);
            }
        }
    }
}

// ---------------- kernel B: fc + normalize + qsim(4-way) + LUT classifier ----------------
#define FC4(acc, v) \
    acc[0] = fmaf(v.x, w0.x, fmaf(v.y, w0.y, fmaf(v.z, w0.z, fmaf(v.w, w0.w, acc[0])))); \
    acc[1] = fmaf(v.x, w1.x, fmaf(v.y, w1.y, fmaf(v.z, w1.z, fmaf(v.w, w1.w, acc[1])))); \
    acc[2] = fmaf(v.x, w2.x, fmaf(v.y, w2.y, fmaf(v.z, w2.z, fmaf(v.w, w2.w, acc[2])))); \
    acc[3] = fmaf(v.x, w3.x, fmaf(v.y, w3.y, fmaf(v.z, w3.z, fmaf(v.w, w3.w, acc[3]))));

#define NORMALIZE(acc, sdst) { \
    float v0 = fmaxf(acc[0] + fb.x, 0.f); \
    float v1 = fmaxf(acc[1] + fb.y, 0.f); \
    float v2 = fmaxf(acc[2] + fb.z, 0.f); \
    float v3 = fmaxf(acc[3] + fb.w, 0.f); \
    float ss = v0 * v0 + v1 * v1 + v2 * v2 + v3 * v3; \
    _Pragma("unroll") \
    for (int m = 1; m < 64; m <<= 1) ss += __shfl_xor(ss, m); \
    float sc = 1.f / fmaxf(sqrtf(ss), 1e-12f); \
    sdst[0] = v0 * sc; sdst[1] = v1 * sc; sdst[2] = v2 * sc; sdst[3] = v3 * sc; \
}

__global__ __launch_bounds__(256)
void qsim_cls(const float* __restrict__ fcw, const float* __restrict__ fcb,
              const float* __restrict__ lut, const float* __restrict__ poolg,
              float* __restrict__ out, int B)
{
    const int tid  = threadIdx.x;
    const int lane = tid & 63;
    const int wv   = tid >> 6;

    const float* qtc = lut + NL;
    const float* qts = lut + NL + 56;

    const int s0 = blockIdx.x * 16 + wv * 4;   // 4 samples per wave
    const int sa = (s0 + 0 < B) ? s0 + 0 : B - 1;
    const int sb = (s0 + 1 < B) ? s0 + 1 : B - 1;
    const int sc_ = (s0 + 2 < B) ? s0 + 2 : B - 1;
    const int sd = (s0 + 3 < B) ? s0 + 3 : B - 1;

    const float4* pvA = (const float4*)(poolg + (size_t)sa * 48);
    const float4* pvB = (const float4*)(poolg + (size_t)sb * 48);
    const float4* pvC = (const float4*)(poolg + (size_t)sc_ * 48);
    const float4* pvD = (const float4*)(poolg + (size_t)sd * 48);

    // ---- fc 48->256 for 4 samples; lane owns outputs 4*lane..4*lane+3 ----
    const int o0 = lane * 4;
    const float4* wr0 = (const float4*)(fcw + (o0 + 0) * 48);
    const float4* wr1 = (const float4*)(fcw + (o0 + 1) * 48);
    const float4* wr2 = (const float4*)(fcw + (o0 + 2) * 48);
    const float4* wr3 = (const float4*)(fcw + (o0 + 3) * 48);

    float aA[4] = {0.f, 0.f, 0.f, 0.f};
    float aB[4] = {0.f, 0.f, 0.f, 0.f};
    float aC[4] = {0.f, 0.f, 0.f, 0.f};
    float aD[4] = {0.f, 0.f, 0.f, 0.f};

    #pragma unroll
    for (int kc = 0; kc < 12; ++kc) {
        float4 w0 = wr0[kc], w1 = wr1[kc], w2 = wr2[kc], w3 = wr3[kc];
        float4 vA = pvA[kc], vB = pvB[kc], vC = pvC[kc], vD = pvD[kc];
        FC4(aA, vA) FC4(aB, vB) FC4(aC, vC) FC4(aD, vD)
    }

    float4 fb = *(const float4*)(fcb + o0);
    float sA[4], sB[4], sC[4], sD[4];
    NORMALIZE(aA, sA) NORMALIZE(aB, sB) NORMALIZE(aC, sC) NORMALIZE(aD, sD)

    // ---- qsim: 56 conjugated rotations on 4 interleaved chains ----
    ROTLAYER4(0) ROTLAYER4(1) ROTLAYER4(2) ROTLAYER4(3)
    ROTLAYER4(4) ROTLAYER4(5) ROTLAYER4(6)

    // ---- measurement: bit7 = lane bit5 ----
    float pA = sA[0]*sA[0] + sA[1]*sA[1] + sA[2]*sA[2] + sA[3]*sA[3];
    float pB = sB[0]*sB[0] + sB[1]*sB[1] + sB[2]*sB[2] + sB[3]*sB[3];
    float pC = sC[0]*sC[0] + sC[1]*sC[1] + sC[2]*sC[2] + sC[3]*sC[3];
    float pD = sD[0]*sD[0] + sD[1]*sD[1] + sD[2]*sD[2] + sD[3]*sD[3];
    if (lane & 32) { pA = -pA; pB = -pB; pC = -pC; pD = -pD; }
    #pragma unroll
    for (int m = 1; m < 64; m <<= 1) {
        pA += __shfl_xor(pA, m); pB += __shfl_xor(pB, m);
        pC += __shfl_xor(pC, m); pD += __shfl_xor(pD, m);
    }

    if (lane < 4) {
        float qout = (lane == 0) ? pA : (lane == 1) ? pB : (lane == 2) ? pC : pD;
        int osample = s0 + lane;
        float u = (qout + 1.f) * 0.5f * (float)(NL - 1);
        int i0 = (int)floorf(u);
        i0 = (i0 < 0) ? 0 : ((i0 > NL - 2) ? NL - 2 : i0);
        float fr = u - (float)i0;
        float z0 = lut[i0], z1 = lut[i0 + 1];
        float z = fmaf(z1 - z0, fr, z0);
        if (osample < B) out[osample] = 1.f / (1.f + expf(-z));
    }
}

extern "C" void kernel_launch(void* const* d_in, const int* in_sizes, int n_in,
                              void* d_out, int out_size, void* d_ws, size_t ws_size,
                              hipStream_t stream) {
    const float* x   = (const float*)d_in[0];
    const float* c1w = (const float*)d_in[1];
    const float* c1b = (const float*)d_in[2];
    const float* c2w = (const float*)d_in[3];
    const float* c2b = (const float*)d_in[4];
    const float* c3w = (const float*)d_in[5];
    const float* c3b = (const float*)d_in[6];
    const float* fcw = (const float*)d_in[7];
    const float* fcb = (const float*)d_in[8];
    const float* qw  = (const float*)d_in[9];
    const float* w1  = (const float*)d_in[10];
    const float* b1  = (const float*)d_in[11];
    const float* w2  = (const float*)d_in[12];
    const float* b2  = (const float*)d_in[13];
    const float* w3  = (const float*)d_in[14];
    const float* b3  = (const float*)d_in[15];
    const float* w4  = (const float*)d_in[16];
    const float* b4  = (const float*)d_in[17];
    const float* w5  = (const float*)d_in[18];
    const float* b5  = (const float*)d_in[19];

    float* lut   = (float*)d_ws;            // [0,NL): z; [NL,NL+112): cos/sin
    float* poolg = (float*)d_ws + POOL_OFF; // B*48 floats

    int B = in_sizes[0] / 784;

    build_lut<<<dim3(NL / 16), dim3(256), 0, stream>>>(
        w1, b1, w2, b2, w3, b3, w4, b4, w5, b5, qw, lut);

    int grid = (B + 15) / 16;
    conv_pool<<<dim3(grid), dim3(256), 0, stream>>>(
        x, c1w, c1b, c2w, c2b, c3w, c3b, poolg, B);

    qsim_cls<<<dim3(grid), dim3(256), 0, stream>>>(
        fcw, fcb, lut, poolg, (float*)d_out, B);
}

// Round 7
// 500.626 us; speedup vs baseline: 3.0294x; 1.3690x over previous
//
#include <hip/hip_runtime.h>
#include <math.h>

// R6: packed-fp32 sample pairing (v_pk_fma_f32 target).
//  A) conv_pool: two samples per lane as float2 through conv1/conv2/conv3/pool.
//     Shared window loads / address math / weights amortized over the pair.
//     LDS 53.2KB/block -> 3 blocks/CU (issue-bound, so occupancy drop is OK).
//  B) qsim_cls: fc + normalize + qsim with chains packed (A,B)->float2, (C,D)->float2.

#define WR2_SZ 1664   // per-wave conv scratch float2s (4 waves * 1664 * 8B = 53248 B/block)
#define NL   16384    // LUT entries
#define POOL_OFF (NL + 128)   // float offset of pooled buffer in d_ws

// Conjugated-rotation masks (verified absmax 0.0 in R2-R5).
constexpr int QM[7][8] = {
 {0x80,0x40,0x20,0x10,0x08,0x04,0x02,0x01},
 {0xC0,0x60,0x30,0x18,0x0C,0x06,0x03,0x01},
 {0xA0,0x50,0x28,0x14,0x0A,0x05,0x02,0x01},
 {0xF0,0x78,0x3C,0x1E,0x0F,0x07,0x03,0x01},
 {0x88,0x44,0x22,0x11,0x08,0x04,0x02,0x01},
 {0xCC,0x66,0x33,0x19,0x0C,0x06,0x03,0x01},
 {0xAA,0x55,0x2A,0x15,0x0A,0x05,0x02,0x01}};
constexpr int QR[7][8] = {
 {0x80,0x40,0x20,0x10,0x08,0x04,0x02,0x01},
 {0x80,0xC0,0xE0,0xF0,0xF8,0xFC,0xFE,0xFF},
 {0x80,0x40,0xA0,0x50,0xA8,0x54,0xAA,0x55},
 {0x80,0xC0,0x60,0x30,0x98,0xCC,0x66,0x33},
 {0x80,0x40,0x20,0x10,0x88,0x44,0x22,0x11},
 {0x80,0xC0,0xE0,0xF0,0x78,0x3C,0x1E,0x0F},
 {0x80,0x40,0xA0,0x50,0x28,0x14,0x0A,0x05}};

// One conjugated rotation on two float2-packed chain-pairs (4 samples).
#define ROTSTEP2(L, Q) { \
    constexpr int m_  = QM[L][Q]; \
    constexpr int r_  = QR[L][Q]; \
    constexpr int lm_ = m_ >> 2, rm_ = m_ & 3; \
    constexpr int rl_ = r_ >> 2, rr_ = r_ & 3; \
    constexpr float f1_ = (rr_ & 1) ? -1.f : 1.f; \
    constexpr float f2_ = (rr_ & 2) ? -1.f : 1.f; \
    constexpr float f3_ = f1_ * f2_; \
    const float c_ = qtc[(L) * 8 + (Q)]; \
    const float s_ = qts[(L) * 8 + (Q)]; \
    float sgn_; \
    if constexpr (rl_ != 0) sgn_ = (__popc(lane & rl_) & 1) ? s_ : -s_; \
    else                    sgn_ = -s_; \
    float2 pU0_ = sU[0 ^ rm_], pU1_ = sU[1 ^ rm_], pU2_ = sU[2 ^ rm_], pU3_ = sU[3 ^ rm_]; \
    float2 pV0_ = sV[0 ^ rm_], pV1_ = sV[1 ^ rm_], pV2_ = sV[2 ^ rm_], pV3_ = sV[3 ^ rm_]; \
    if constexpr (lm_ != 0) { \
        pU0_.x = __shfl_xor(pU0_.x, lm_); pU0_.y = __shfl_xor(pU0_.y, lm_); \
        pU1_.x = __shfl_xor(pU1_.x, lm_); pU1_.y = __shfl_xor(pU1_.y, lm_); \
        pU2_.x = __shfl_xor(pU2_.x, lm_); pU2_.y = __shfl_xor(pU2_.y, lm_); \
        pU3_.x = __shfl_xor(pU3_.x, lm_); pU3_.y = __shfl_xor(pU3_.y, lm_); \
        pV0_.x = __shfl_xor(pV0_.x, lm_); pV0_.y = __shfl_xor(pV0_.y, lm_); \
        pV1_.x = __shfl_xor(pV1_.x, lm_); pV1_.y = __shfl_xor(pV1_.y, lm_); \
        pV2_.x = __shfl_xor(pV2_.x, lm_); pV2_.y = __shfl_xor(pV2_.y, lm_); \
        pV3_.x = __shfl_xor(pV3_.x, lm_); pV3_.y = __shfl_xor(pV3_.y, lm_); \
    } \
    sU[0].x = fmaf(c_, sU[0].x, sgn_ * pU0_.x); \
    sU[0].y = fmaf(c_, sU[0].y, sgn_ * pU0_.y); \
    sU[1].x = fmaf(c_, sU[1].x, (f1_ * sgn_) * pU1_.x); \
    sU[1].y = fmaf(c_, sU[1].y, (f1_ * sgn_) * pU1_.y); \
    sU[2].x = fmaf(c_, sU[2].x, (f2_ * sgn_) * pU2_.x); \
    sU[2].y = fmaf(c_, sU[2].y, (f2_ * sgn_) * pU2_.y); \
    sU[3].x = fmaf(c_, sU[3].x, (f3_ * sgn_) * pU3_.x); \
    sU[3].y = fmaf(c_, sU[3].y, (f3_ * sgn_) * pU3_.y); \
    sV[0].x = fmaf(c_, sV[0].x, sgn_ * pV0_.x); \
    sV[0].y = fmaf(c_, sV[0].y, sgn_ * pV0_.y); \
    sV[1].x = fmaf(c_, sV[1].x, (f1_ * sgn_) * pV1_.x); \
    sV[1].y = fmaf(c_, sV[1].y, (f1_ * sgn_) * pV1_.y); \
    sV[2].x = fmaf(c_, sV[2].x, (f2_ * sgn_) * pV2_.x); \
    sV[2].y = fmaf(c_, sV[2].y, (f2_ * sgn_) * pV2_.y); \
    sV[3].x = fmaf(c_, sV[3].x, (f3_ * sgn_) * pV3_.x); \
    sV[3].y = fmaf(c_, sV[3].y, (f3_ * sgn_) * pV3_.y); \
}

#define ROTLAYER2(L) \
    ROTSTEP2(L,0) ROTSTEP2(L,1) ROTSTEP2(L,2) ROTSTEP2(L,3) \
    ROTSTEP2(L,4) ROTSTEP2(L,5) ROTSTEP2(L,6) ROTSTEP2(L,7)

// ---------------- LUT builder ----------------
__global__ __launch_bounds__(256)
void build_lut(const float* __restrict__ w1, const float* __restrict__ b1,
               const float* __restrict__ w2, const float* __restrict__ b2,
               const float* __restrict__ w3, const float* __restrict__ b3,
               const float* __restrict__ w4, const float* __restrict__ b4,
               const float* __restrict__ w5, const float* __restrict__ b5,
               const float* __restrict__ qw,
               float* __restrict__ lut)
{
    __shared__ float hh[16][344];
    const int tid = threadIdx.x;
    const int e = tid >> 4;
    const int w = tid & 15;
    const int idx = blockIdx.x * 16 + e;
    const float t = -1.f + 2.f * (float)idx / (float)(NL - 1);

    if (blockIdx.x == 0 && tid < 56) {
        float th = 0.5f * qw[tid];
        lut[NL + tid]      = cosf(th);
        lut[NL + 56 + tid] = sinf(th);
    }

    float* hA = hh[e];
    float* hB = hA + 184;

    #pragma unroll
    for (int tt = 0; tt < 12; ++tt) {
        int j = tt * 16 + w;
        if (j < 180) hA[j] = fmaxf(fmaf(t, w1[j], b1[j]), 0.f);
    }
    for (int tt = 0; tt < 9; ++tt) {
        int j = tt * 16 + w;
        int jj = (j < 140) ? j : 0;
        const float4* wrow = (const float4*)(w2 + jj * 180);
        float a0 = 0.f, a1 = 0.f, a2 = 0.f, a3 = 0.f;
        for (int kc = 0; kc < 45; ++kc) {
            float4 h4 = *(const float4*)(hA + kc * 4);
            float4 ww = wrow[kc];
            a0 = fmaf(h4.x, ww.x, a0); a1 = fmaf(h4.y, ww.y, a1);
            a2 = fmaf(h4.z, ww.z, a2); a3 = fmaf(h4.w, ww.w, a3);
        }
        if (j < 140) hB[j] = fmaxf((a0 + a1) + (a2 + a3) + b2[j], 0.f);
    }
    for (int tt = 0; tt < 7; ++tt) {
        int j = tt * 16 + w;
        int jj = (j < 100) ? j : 0;
        const float4* wrow = (const float4*)(w3 + jj * 140);
        float a0 = 0.f, a1 = 0.f, a2 = 0.f, a3 = 0.f;
        for (int kc = 0; kc < 35; ++kc) {
            float4 h4 = *(const float4*)(hB + kc * 4);
            float4 ww = wrow[kc];
            a0 = fmaf(h4.x, ww.x, a0); a1 = fmaf(h4.y, ww.y, a1);
            a2 = fmaf(h4.z, ww.z, a2); a3 = fmaf(h4.w, ww.w, a3);
        }
        if (j < 100) hA[j] = fmaxf((a0 + a1) + (a2 + a3) + b3[j], 0.f);
    }
    for (int tt = 0; tt < 4; ++tt) {
        int j = tt * 16 + w;
        int jj = (j < 50) ? j : 0;
        const float4* wrow = (const float4*)(w4 + jj * 100);
        float a0 = 0.f, a1 = 0.f, a2 = 0.f, a3 = 0.f;
        for (int kc = 0; kc < 25; ++kc) {
            float4 h4 = *(const float4*)(hA + kc * 4);
            float4 ww = wrow[kc];
            a0 = fmaf(h4.x, ww.x, a0); a1 = fmaf(h4.y, ww.y, a1);
            a2 = fmaf(h4.z, ww.z, a2); a3 = fmaf(h4.w, ww.w, a3);
        }
        if (j < 50) hB[j] = fmaxf((a0 + a1) + (a2 + a3) + b4[j], 0.f);
    }
    float p5 = 0.f;
    for (int k = w; k < 50; k += 16) p5 = fmaf(hB[k], w5[k], p5);
    #pragma unroll
    for (int m = 1; m < 16; m <<= 1) p5 += __shfl_xor(p5, m);
    if (w == 0) lut[idx] = p5 + b5[0];
}

// ---------------- kernel A: convs + pool, 2 samples/lane as float2 ----------------
__global__ __launch_bounds__(256, 3)
void conv_pool(const float* __restrict__ x,
               const float* __restrict__ c1w, const float* __restrict__ c1b,
               const float* __restrict__ c2w, const float* __restrict__ c2b,
               const float* __restrict__ c3w, const float* __restrict__ c3b,
               float* __restrict__ poolg, int B)
{
    __shared__ float2 wreg2[4][WR2_SZ];

    const int tid  = threadIdx.x;
    const int lane = tid & 63;
    const int wv   = tid >> 6;

    float2* wr2 = wreg2[wv];
    const int base = blockIdx.x * 16;

    // float2 layout per wave (indices as R5's float layout):
    //   c1p2 : [0, 672)    = [3][14][16], col c at c+1
    //   pin2 : [672, 1664) = 31x32 input (pad 2); dead after conv1
    //   c2pT2: [672, 1320) = [81 pos][8 ch]; overlays pin2
    //   c3_2 : [0, 588)    = 12*49; overlays dead c1p2
    float2* c1p2  = wr2;
    float2* pin2  = wr2 + 672;
    float2* c2pT2 = wr2 + 672;
    float2* c3_2  = wr2;

    for (int pr = 0; pr < 2; ++pr) {
        const int sa = base + wv * 4 + pr * 2;
        if (sa >= B) break;
        const int sb = (sa + 1 < B) ? sa + 1 : sa;

        // zero whole scratch: 1664 float2 = 3328 floats = 13 float4-stores/lane
        {
            float4 z4 = {0.f, 0.f, 0.f, 0.f};
            float* w0 = (float*)wr2;
            #pragma unroll
            for (int t = 0; t < 13; ++t)
                *(float4*)(w0 + t * 256 + lane * 4) = z4;
        }
        // interleaved input load: pin2[i] = {xa[i], xb[i]}
        {
            const float4* xsA = (const float4*)(x + (size_t)sa * 784);
            const float4* xsB = (const float4*)(x + (size_t)sb * 784);
            #pragma unroll
            for (int t = 0; t < 4; ++t) {
                int i4 = t * 64 + lane;
                if (i4 < 196) {
                    float4 va = xsA[i4];
                    float4 vb = xsB[i4];
                    int r = i4 / 7;
                    int c = (i4 % 7) * 4;
                    float2* dst = pin2 + (r + 2) * 32 + (c + 2);
                    dst[0] = make_float2(va.x, vb.x);
                    dst[1] = make_float2(va.y, vb.y);
                    dst[2] = make_float2(va.z, vb.z);
                    dst[3] = make_float2(va.w, vb.w);
                }
            }
        }

        // ---- conv1: k5 s2 p2 -> c1p2 [3][14][16] (col+1) ----
        #pragma unroll
        for (int t = 0; t < 4; ++t) {
            int p = t * 64 + lane;
            bool valid = p < 196;
            int pp = valid ? p : 0;
            int y = pp / 14, xx = pp % 14;
            const float2* pr2 = pin2 + (2 * y) * 32 + 2 * xx;
            float2 win[25];
            #pragma unroll
            for (int ky = 0; ky < 5; ++ky) {
                const float2* rw = pr2 + ky * 32;
                #pragma unroll
                for (int j = 0; j < 5; ++j) win[ky * 5 + j] = rw[j];
            }
            #pragma unroll
            for (int c = 0; c < 3; ++c) {
                float ax = c1b[c], ay = c1b[c];
                #pragma unroll
                for (int k = 0; k < 25; ++k) {
                    float wk = c1w[c * 25 + k];
                    ax = fmaf(win[k].x, wk, ax);
                    ay = fmaf(win[k].y, wk, ay);
                }
                if (valid)
                    c1p2[c * 224 + y * 16 + (xx + 1)] =
                        make_float2(fmaxf(ax, 0.f), fmaxf(ay, 0.f));
            }
        }

        // ---- conv2: k3 s2 p1 -> c2pT2 [81][8] (row-masked top row) ----
        {
            // zero c2pT2: 648 float2 = 324 float4
            float4 z4 = {0.f, 0.f, 0.f, 0.f};
            float4* zz = (float4*)c2pT2;
            #pragma unroll
            for (int t = 0; t < 6; ++t) {
                int i = t * 64 + lane;
                if (i < 324) zz[i] = z4;
            }
        }
        {
            int p = lane;
            bool valid = p < 49;
            int pp = valid ? p : 0;
            int y = pp / 7, xx = pp % 7;
            float acx[6], acy[6];
            #pragma unroll
            for (int c = 0; c < 6; ++c) { acx[c] = c2b[c]; acy[c] = c2b[c]; }
            #pragma unroll
            for (int ic = 0; ic < 3; ++ic) {
                const float2* bic = c1p2 + ic * 224;
                float2 win[9];
                #pragma unroll
                for (int ky = 0; ky < 3; ++ky) {
                    int rr = 2 * y - 1 + ky;           // [-1,13]; only -1 invalid
                    bool okr = rr >= 0;
                    int rc = okr ? rr : 0;
                    const float2* rw = bic + rc * 16 + 2 * xx;
                    float2 a0 = rw[0], a1 = rw[1], a2 = rw[2];
                    float2 z2 = {0.f, 0.f};
                    win[ky * 3 + 0] = okr ? a0 : z2;
                    win[ky * 3 + 1] = okr ? a1 : z2;
                    win[ky * 3 + 2] = okr ? a2 : z2;
                }
                #pragma unroll
                for (int c = 0; c < 6; ++c)
                    #pragma unroll
                    for (int k = 0; k < 9; ++k) {
                        float wk = c2w[c * 27 + ic * 9 + k];
                        acx[c] = fmaf(win[k].x, wk, acx[c]);
                        acy[c] = fmaf(win[k].y, wk, acy[c]);
                    }
            }
            if (valid) {
                float2* op = c2pT2 + ((y + 1) * 9 + (xx + 1)) * 8;
                #pragma unroll
                for (int c = 0; c < 6; ++c)
                    op[c] = make_float2(fmaxf(acx[c], 0.f), fmaxf(acy[c], 0.f));
            }
        }

        // ---- conv3: k3 s1 p1 -> c3_2 (over dead c1p2) ----
        {
            int p = lane;
            bool valid = p < 49;
            int pp = valid ? p : 0;
            int y = pp / 7, xx = pp % 7;
            float acx[12], acy[12];
            #pragma unroll
            for (int c = 0; c < 12; ++c) { acx[c] = c3b[c]; acy[c] = c3b[c]; }
            #pragma unroll
            for (int dy = 0; dy < 3; ++dy)
                #pragma unroll
                for (int dx = 0; dx < 3; ++dx) {
                    const float2* cp = c2pT2 + ((y + dy) * 9 + (xx + dx)) * 8;
                    float2 ch[6];
                    #pragma unroll
                    for (int j = 0; j < 6; ++j) ch[j] = cp[j];
                    const int k = dy * 3 + dx;
                    #pragma unroll
                    for (int c = 0; c < 12; ++c) {
                        const float* wp = c3w + c * 54 + k;
                        #pragma unroll
                        for (int j = 0; j < 6; ++j) {
                            float wk = wp[j * 9];
                            acx[c] = fmaf(ch[j].x, wk, acx[c]);
                            acy[c] = fmaf(ch[j].y, wk, acy[c]);
                        }
                    }
                }
            if (valid) {
                #pragma unroll
                for (int c = 0; c < 12; ++c)
                    c3_2[c * 49 + p] = make_float2(fmaxf(acx[c], 0.f), fmaxf(acy[c], 0.f));
            }
        }

        // ---- adaptive pool -> poolg for both samples ----
        {
            int o = lane;
            if (o < 48) {
                int c = o >> 2, i = (o >> 1) & 1, j = o & 1;
                int ri = i * 3, cj = j * 3;
                float sx = 0.f, sy = 0.f;
                #pragma unroll
                for (int dy = 0; dy < 4; ++dy)
                    #pragma unroll
                    for (int dx = 0; dx < 4; ++dx) {
                        float2 v = c3_2[c * 49 + (ri + dy) * 7 + (cj + dx)];
                        sx += v.x; sy += v.y;
                    }
                poolg[(size_t)sa * 48 + o] = sx * (1.f / 16.f);
                if (sb != sa) poolg[(size_t)sb * 48 + o] = sy * (1.f / 16.f);
            }
        }
    }
}

// ---------------- kernel B: fc + normalize + packed qsim + LUT classifier ----------------
__global__ __launch_bounds__(256)
void qsim_cls(const float* __restrict__ fcw, const float* __restrict__ fcb,
              const float* __restrict__ lut, const float* __restrict__ poolg,
              float* __restrict__ out, int B)
{
    const int tid  = threadIdx.x;
    const int lane = tid & 63;
    const int wv   = tid >> 6;

    const float* qtc = lut + NL;
    const float* qts = lut + NL + 56;

    const int s0 = blockIdx.x * 16 + wv * 4;   // 4 samples per wave
    const int sa = (s0 + 0 < B) ? s0 + 0 : B - 1;
    const int sb = (s0 + 1 < B) ? s0 + 1 : B - 1;
    const int sc_ = (s0 + 2 < B) ? s0 + 2 : B - 1;
    const int sd = (s0 + 3 < B) ? s0 + 3 : B - 1;

    const float4* pvA = (const float4*)(poolg + (size_t)sa * 48);
    const float4* pvB = (const float4*)(poolg + (size_t)sb * 48);
    const float4* pvC = (const float4*)(poolg + (size_t)sc_ * 48);
    const float4* pvD = (const float4*)(poolg + (size_t)sd * 48);

    // fc 48->256, outputs packed: U = (A,B), V = (C,D)
    const int o0 = lane * 4;
    const float4* wr0 = (const float4*)(fcw + (o0 + 0) * 48);
    const float4* wr1 = (const float4*)(fcw + (o0 + 1) * 48);
    const float4* wr2 = (const float4*)(fcw + (o0 + 2) * 48);
    const float4* wr3 = (const float4*)(fcw + (o0 + 3) * 48);

    float2 aU[4], aV[4];
    #pragma unroll
    for (int j = 0; j < 4; ++j) { aU[j] = make_float2(0.f, 0.f); aV[j] = make_float2(0.f, 0.f); }

    #pragma unroll
    for (int kc = 0; kc < 12; ++kc) {
        float4 w0 = wr0[kc], w1 = wr1[kc], w2 = wr2[kc], w3 = wr3[kc];
        float4 vA = pvA[kc], vB = pvB[kc], vC = pvC[kc], vD = pvD[kc];
        aU[0].x = fmaf(vA.x, w0.x, fmaf(vA.y, w0.y, fmaf(vA.z, w0.z, fmaf(vA.w, w0.w, aU[0].x))));
        aU[0].y = fmaf(vB.x, w0.x, fmaf(vB.y, w0.y, fmaf(vB.z, w0.z, fmaf(vB.w, w0.w, aU[0].y))));
        aU[1].x = fmaf(vA.x, w1.x, fmaf(vA.y, w1.y, fmaf(vA.z, w1.z, fmaf(vA.w, w1.w, aU[1].x))));
        aU[1].y = fmaf(vB.x, w1.x, fmaf(vB.y, w1.y, fmaf(vB.z, w1.z, fmaf(vB.w, w1.w, aU[1].y))));
        aU[2].x = fmaf(vA.x, w2.x, fmaf(vA.y, w2.y, fmaf(vA.z, w2.z, fmaf(vA.w, w2.w, aU[2].x))));
        aU[2].y = fmaf(vB.x, w2.x, fmaf(vB.y, w2.y, fmaf(vB.z, w2.z, fmaf(vB.w, w2.w, aU[2].y))));
        aU[3].x = fmaf(vA.x, w3.x, fmaf(vA.y, w3.y, fmaf(vA.z, w3.z, fmaf(vA.w, w3.w, aU[3].x))));
        aU[3].y = fmaf(vB.x, w3.x, fmaf(vB.y, w3.y, fmaf(vB.z, w3.z, fmaf(vB.w, w3.w, aU[3].y))));
        aV[0].x = fmaf(vC.x, w0.x, fmaf(vC.y, w0.y, fmaf(vC.z, w0.z, fmaf(vC.w, w0.w, aV[0].x))));
        aV[0].y = fmaf(vD.x, w0.x, fmaf(vD.y, w0.y, fmaf(vD.z, w0.z, fmaf(vD.w, w0.w, aV[0].y))));
        aV[1].x = fmaf(vC.x, w1.x, fmaf(vC.y, w1.y, fmaf(vC.z, w1.z, fmaf(vC.w, w1.w, aV[1].x))));
        aV[1].y = fmaf(vD.x, w1.x, fmaf(vD.y, w1.y, fmaf(vD.z, w1.z, fmaf(vD.w, w1.w, aV[1].y))));
        aV[2].x = fmaf(vC.x, w2.x, fmaf(vC.y, w2.y, fmaf(vC.z, w2.z, fmaf(vC.w, w2.w, aV[2].x))));
        aV[2].y = fmaf(vD.x, w2.x, fmaf(vD.y, w2.y, fmaf(vD.z, w2.z, fmaf(vD.w, w2.w, aV[2].y))));
        aV[3].x = fmaf(vC.x, w3.x, fmaf(vC.y, w3.y, fmaf(vC.z, w3.z, fmaf(vC.w, w3.w, aV[3].x))));
        aV[3].y = fmaf(vD.x, w3.x, fmaf(vD.y, w3.y, fmaf(vD.z, w3.z, fmaf(vD.w, w3.w, aV[3].y))));
    }

    float4 fb = *(const float4*)(fcb + o0);
    const float fbv[4] = {fb.x, fb.y, fb.z, fb.w};

    float2 sU[4], sV[4];
    {
        float2 ssU = make_float2(0.f, 0.f), ssV = make_float2(0.f, 0.f);
        #pragma unroll
        for (int j = 0; j < 4; ++j) {
            sU[j].x = fmaxf(aU[j].x + fbv[j], 0.f);
            sU[j].y = fmaxf(aU[j].y + fbv[j], 0.f);
            sV[j].x = fmaxf(aV[j].x + fbv[j], 0.f);
            sV[j].y = fmaxf(aV[j].y + fbv[j], 0.f);
            ssU.x = fmaf(sU[j].x, sU[j].x, ssU.x);
            ssU.y = fmaf(sU[j].y, sU[j].y, ssU.y);
            ssV.x = fmaf(sV[j].x, sV[j].x, ssV.x);
            ssV.y = fmaf(sV[j].y, sV[j].y, ssV.y);
        }
        #pragma unroll
        for (int m = 1; m < 64; m <<= 1) {
            ssU.x += __shfl_xor(ssU.x, m); ssU.y += __shfl_xor(ssU.y, m);
            ssV.x += __shfl_xor(ssV.x, m); ssV.y += __shfl_xor(ssV.y, m);
        }
        float scUx = 1.f / fmaxf(sqrtf(ssU.x), 1e-12f);
        float scUy = 1.f / fmaxf(sqrtf(ssU.y), 1e-12f);
        float scVx = 1.f / fmaxf(sqrtf(ssV.x), 1e-12f);
        float scVy = 1.f / fmaxf(sqrtf(ssV.y), 1e-12f);
        #pragma unroll
        for (int j = 0; j < 4; ++j) {
            sU[j].x *= scUx; sU[j].y *= scUy;
            sV[j].x *= scVx; sV[j].y *= scVy;
        }
    }

    // qsim: 56 conjugated rotations on 2 packed chain-pairs
    ROTLAYER2(0) ROTLAYER2(1) ROTLAYER2(2) ROTLAYER2(3)
    ROTLAYER2(4) ROTLAYER2(5) ROTLAYER2(6)

    // measurement: bit7 = lane bit5
    float2 pU, pV;
    pU.x = sU[0].x*sU[0].x + sU[1].x*sU[1].x + sU[2].x*sU[2].x + sU[3].x*sU[3].x;
    pU.y = sU[0].y*sU[0].y + sU[1].y*sU[1].y + sU[2].y*sU[2].y + sU[3].y*sU[3].y;
    pV.x = sV[0].x*sV[0].x + sV[1].x*sV[1].x + sV[2].x*sV[2].x + sV[3].x*sV[3].x;
    pV.y = sV[0].y*sV[0].y + sV[1].y*sV[1].y + sV[2].y*sV[2].y + sV[3].y*sV[3].y;
    if (lane & 32) { pU.x = -pU.x; pU.y = -pU.y; pV.x = -pV.x; pV.y = -pV.y; }
    #pragma unroll
    for (int m = 1; m < 64; m <<= 1) {
        pU.x += __shfl_xor(pU.x, m); pU.y += __shfl_xor(pU.y, m);
        pV.x += __shfl_xor(pV.x, m); pV.y += __shfl_xor(pV.y, m);
    }

    if (lane < 4) {
        float qout = (lane == 0) ? pU.x : (lane == 1) ? pU.y : (lane == 2) ? pV.x : pV.y;
        int osample = s0 + lane;
        float u = (qout + 1.f) * 0.5f * (float)(NL - 1);
        int i0 = (int)floorf(u);
        i0 = (i0 < 0) ? 0 : ((i0 > NL - 2) ? NL - 2 : i0);
        float fr = u - (float)i0;
        float z0 = lut[i0], z1 = lut[i0 + 1];
        float z = fmaf(z1 - z0, fr, z0);
        if (osample < B) out[osample] = 1.f / (1.f + expf(-z));
    }
}

extern "C" void kernel_launch(void* const* d_in, const int* in_sizes, int n_in,
                              void* d_out, int out_size, void* d_ws, size_t ws_size,
                              hipStream_t stream) {
    const float* x   = (const float*)d_in[0];
    const float* c1w = (const float*)d_in[1];
    const float* c1b = (const float*)d_in[2];
    const float* c2w = (const float*)d_in[3];
    const float* c2b = (const float*)d_in[4];
    const float* c3w = (const float*)d_in[5];
    const float* c3b = (const float*)d_in[6];
    const float* fcw = (const float*)d_in[7];
    const float* fcb = (const float*)d_in[8];
    const float* qw  = (const float*)d_in[9];
    const float* w1  = (const float*)d_in[10];
    const float* b1  = (const float*)d_in[11];
    const float* w2  = (const float*)d_in[12];
    const float* b2  = (const float*)d_in[13];
    const float* w3  = (const float*)d_in[14];
    const float* b3  = (const float*)d_in[15];
    const float* w4  = (const float*)d_in[16];
    const float* b4  = (const float*)d_in[17];
    const float* w5  = (const float*)d_in[18];
    const float* b5  = (const float*)d_in[19];

    float* lut   = (float*)d_ws;            // [0,NL): z; [NL,NL+112): cos/sin
    float* poolg = (float*)d_ws + POOL_OFF; // B*48 floats

    int B = in_sizes[0] / 784;

    build_lut<<<dim3(NL / 16), dim3(256), 0, stream>>>(
        w1, b1, w2, b2, w3, b3, w4, b4, w5, b5, qw, lut);

    int grid = (B + 15) / 16;
    conv_pool<<<dim3(grid), dim3(256), 0, stream>>>(
        x, c1w, c1b, c2w, c2b, c3w, c3b, poolg, B);

    qsim_cls<<<dim3(grid), dim3(256), 0, stream>>>(
        fcw, fcb, lut, poolg, (float*)d_out, B);
}

// Round 8
// 478.401 us; speedup vs baseline: 3.1701x; 1.0465x over previous
//
#include <hip/hip_runtime.h>
#include <math.h>

// R7: single fused kernel (conv pair-packed + FC + normalize + packed qsim + LUT).
//     conv's VALU-issue-bound work and qsim's DS/shuffle-chain work now coexist
//     on each CU and overlap across waves. Only 8 floats (sU) live across the
//     second pair's conv -> no R4-style spill. Pooled stays in LDS.

#define WR2_SZ 1664   // per-wave conv scratch float2s (4 waves * 1664 * 8B = 53248 B/block)
#define NL   16384    // LUT entries

// Conjugated-rotation masks (verified absmax 0.0 in R2-R6).
constexpr int QM[7][8] = {
 {0x80,0x40,0x20,0x10,0x08,0x04,0x02,0x01},
 {0xC0,0x60,0x30,0x18,0x0C,0x06,0x03,0x01},
 {0xA0,0x50,0x28,0x14,0x0A,0x05,0x02,0x01},
 {0xF0,0x78,0x3C,0x1E,0x0F,0x07,0x03,0x01},
 {0x88,0x44,0x22,0x11,0x08,0x04,0x02,0x01},
 {0xCC,0x66,0x33,0x19,0x0C,0x06,0x03,0x01},
 {0xAA,0x55,0x2A,0x15,0x0A,0x05,0x02,0x01}};
constexpr int QR[7][8] = {
 {0x80,0x40,0x20,0x10,0x08,0x04,0x02,0x01},
 {0x80,0xC0,0xE0,0xF0,0xF8,0xFC,0xFE,0xFF},
 {0x80,0x40,0xA0,0x50,0xA8,0x54,0xAA,0x55},
 {0x80,0xC0,0x60,0x30,0x98,0xCC,0x66,0x33},
 {0x80,0x40,0x20,0x10,0x88,0x44,0x22,0x11},
 {0x80,0xC0,0xE0,0xF0,0x78,0x3C,0x1E,0x0F},
 {0x80,0x40,0xA0,0x50,0x28,0x14,0x0A,0x05}};

// One conjugated rotation on two float2-packed chain-pairs (4 samples).
#define ROTSTEP2(L, Q) { \
    constexpr int m_  = QM[L][Q]; \
    constexpr int r_  = QR[L][Q]; \
    constexpr int lm_ = m_ >> 2, rm_ = m_ & 3; \
    constexpr int rl_ = r_ >> 2, rr_ = r_ & 3; \
    constexpr float f1_ = (rr_ & 1) ? -1.f : 1.f; \
    constexpr float f2_ = (rr_ & 2) ? -1.f : 1.f; \
    constexpr float f3_ = f1_ * f2_; \
    const float c_ = qtc[(L) * 8 + (Q)]; \
    const float s_ = qts[(L) * 8 + (Q)]; \
    float sgn_; \
    if constexpr (rl_ != 0) sgn_ = (__popc(lane & rl_) & 1) ? s_ : -s_; \
    else                    sgn_ = -s_; \
    float2 pU0_ = sU[0 ^ rm_], pU1_ = sU[1 ^ rm_], pU2_ = sU[2 ^ rm_], pU3_ = sU[3 ^ rm_]; \
    float2 pV0_ = sV[0 ^ rm_], pV1_ = sV[1 ^ rm_], pV2_ = sV[2 ^ rm_], pV3_ = sV[3 ^ rm_]; \
    if constexpr (lm_ != 0) { \
        pU0_.x = __shfl_xor(pU0_.x, lm_); pU0_.y = __shfl_xor(pU0_.y, lm_); \
        pU1_.x = __shfl_xor(pU1_.x, lm_); pU1_.y = __shfl_xor(pU1_.y, lm_); \
        pU2_.x = __shfl_xor(pU2_.x, lm_); pU2_.y = __shfl_xor(pU2_.y, lm_); \
        pU3_.x = __shfl_xor(pU3_.x, lm_); pU3_.y = __shfl_xor(pU3_.y, lm_); \
        pV0_.x = __shfl_xor(pV0_.x, lm_); pV0_.y = __shfl_xor(pV0_.y, lm_); \
        pV1_.x = __shfl_xor(pV1_.x, lm_); pV1_.y = __shfl_xor(pV1_.y, lm_); \
        pV2_.x = __shfl_xor(pV2_.x, lm_); pV2_.y = __shfl_xor(pV2_.y, lm_); \
        pV3_.x = __shfl_xor(pV3_.x, lm_); pV3_.y = __shfl_xor(pV3_.y, lm_); \
    } \
    sU[0].x = fmaf(c_, sU[0].x, sgn_ * pU0_.x); \
    sU[0].y = fmaf(c_, sU[0].y, sgn_ * pU0_.y); \
    sU[1].x = fmaf(c_, sU[1].x, (f1_ * sgn_) * pU1_.x); \
    sU[1].y = fmaf(c_, sU[1].y, (f1_ * sgn_) * pU1_.y); \
    sU[2].x = fmaf(c_, sU[2].x, (f2_ * sgn_) * pU2_.x); \
    sU[2].y = fmaf(c_, sU[2].y, (f2_ * sgn_) * pU2_.y); \
    sU[3].x = fmaf(c_, sU[3].x, (f3_ * sgn_) * pU3_.x); \
    sU[3].y = fmaf(c_, sU[3].y, (f3_ * sgn_) * pU3_.y); \
    sV[0].x = fmaf(c_, sV[0].x, sgn_ * pV0_.x); \
    sV[0].y = fmaf(c_, sV[0].y, sgn_ * pV0_.y); \
    sV[1].x = fmaf(c_, sV[1].x, (f1_ * sgn_) * pV1_.x); \
    sV[1].y = fmaf(c_, sV[1].y, (f1_ * sgn_) * pV1_.y); \
    sV[2].x = fmaf(c_, sV[2].x, (f2_ * sgn_) * pV2_.x); \
    sV[2].y = fmaf(c_, sV[2].y, (f2_ * sgn_) * pV2_.y); \
    sV[3].x = fmaf(c_, sV[3].x, (f3_ * sgn_) * pV3_.x); \
    sV[3].y = fmaf(c_, sV[3].y, (f3_ * sgn_) * pV3_.y); \
}

#define ROTLAYER2(L) \
    ROTSTEP2(L,0) ROTSTEP2(L,1) ROTSTEP2(L,2) ROTSTEP2(L,3) \
    ROTSTEP2(L,4) ROTSTEP2(L,5) ROTSTEP2(L,6) ROTSTEP2(L,7)

// ---------------- LUT builder ----------------
__global__ __launch_bounds__(256)
void build_lut(const float* __restrict__ w1, const float* __restrict__ b1,
               const float* __restrict__ w2, const float* __restrict__ b2,
               const float* __restrict__ w3, const float* __restrict__ b3,
               const float* __restrict__ w4, const float* __restrict__ b4,
               const float* __restrict__ w5, const float* __restrict__ b5,
               const float* __restrict__ qw,
               float* __restrict__ lut)
{
    __shared__ float hh[16][344];
    const int tid = threadIdx.x;
    const int e = tid >> 4;
    const int w = tid & 15;
    const int idx = blockIdx.x * 16 + e;
    const float t = -1.f + 2.f * (float)idx / (float)(NL - 1);

    if (blockIdx.x == 0 && tid < 56) {
        float th = 0.5f * qw[tid];
        lut[NL + tid]      = cosf(th);
        lut[NL + 56 + tid] = sinf(th);
    }

    float* hA = hh[e];
    float* hB = hA + 184;

    #pragma unroll
    for (int tt = 0; tt < 12; ++tt) {
        int j = tt * 16 + w;
        if (j < 180) hA[j] = fmaxf(fmaf(t, w1[j], b1[j]), 0.f);
    }
    for (int tt = 0; tt < 9; ++tt) {
        int j = tt * 16 + w;
        int jj = (j < 140) ? j : 0;
        const float4* wrow = (const float4*)(w2 + jj * 180);
        float a0 = 0.f, a1 = 0.f, a2 = 0.f, a3 = 0.f;
        for (int kc = 0; kc < 45; ++kc) {
            float4 h4 = *(const float4*)(hA + kc * 4);
            float4 ww = wrow[kc];
            a0 = fmaf(h4.x, ww.x, a0); a1 = fmaf(h4.y, ww.y, a1);
            a2 = fmaf(h4.z, ww.z, a2); a3 = fmaf(h4.w, ww.w, a3);
        }
        if (j < 140) hB[j] = fmaxf((a0 + a1) + (a2 + a3) + b2[j], 0.f);
    }
    for (int tt = 0; tt < 7; ++tt) {
        int j = tt * 16 + w;
        int jj = (j < 100) ? j : 0;
        const float4* wrow = (const float4*)(w3 + jj * 140);
        float a0 = 0.f, a1 = 0.f, a2 = 0.f, a3 = 0.f;
        for (int kc = 0; kc < 35; ++kc) {
            float4 h4 = *(const float4*)(hB + kc * 4);
            float4 ww = wrow[kc];
            a0 = fmaf(h4.x, ww.x, a0); a1 = fmaf(h4.y, ww.y, a1);
            a2 = fmaf(h4.z, ww.z, a2); a3 = fmaf(h4.w, ww.w, a3);
        }
        if (j < 100) hA[j] = fmaxf((a0 + a1) + (a2 + a3) + b3[j], 0.f);
    }
    for (int tt = 0; tt < 4; ++tt) {
        int j = tt * 16 + w;
        int jj = (j < 50) ? j : 0;
        const float4* wrow = (const float4*)(w4 + jj * 100);
        float a0 = 0.f, a1 = 0.f, a2 = 0.f, a3 = 0.f;
        for (int kc = 0; kc < 25; ++kc) {
            float4 h4 = *(const float4*)(hA + kc * 4);
            float4 ww = wrow[kc];
            a0 = fmaf(h4.x, ww.x, a0); a1 = fmaf(h4.y, ww.y, a1);
            a2 = fmaf(h4.z, ww.z, a2); a3 = fmaf(h4.w, ww.w, a3);
        }
        if (j < 50) hB[j] = fmaxf((a0 + a1) + (a2 + a3) + b4[j], 0.f);
    }
    float p5 = 0.f;
    for (int k = w; k < 50; k += 16) p5 = fmaf(hB[k], w5[k], p5);
    #pragma unroll
    for (int m = 1; m < 16; m <<= 1) p5 += __shfl_xor(p5, m);
    if (w == 0) lut[idx] = p5 + b5[0];
}

// ---------------- fused main kernel ----------------
__global__ __launch_bounds__(256, 3)
void fused_all(const float* __restrict__ x,
               const float* __restrict__ c1w, const float* __restrict__ c1b,
               const float* __restrict__ c2w, const float* __restrict__ c2b,
               const float* __restrict__ c3w, const float* __restrict__ c3b,
               const float* __restrict__ fcw, const float* __restrict__ fcb,
               const float* __restrict__ lut,
               float* __restrict__ out, int B)
{
    __shared__ float2 wreg2[4][WR2_SZ];

    const int tid  = threadIdx.x;
    const int lane = tid & 63;
    const int wv   = tid >> 6;

    const float* qtc = lut + NL;
    const float* qts = lut + NL + 56;

    float2* wr2 = wreg2[wv];
    const int base = blockIdx.x * 16;

    // float2 layout per wave:
    //   c1p2   : [0, 672)    = [3][14][16], col c at c+1
    //   pin2   : [672, 1664) = 31x32 input (pad 2); dead after conv1
    //   c2pT2  : [672, 1320) = [81 pos][8 ch]; overlays pin2
    //   c3_2   : [0, 588)    = 12*49; overlays dead c1p2
    //   pooled2: [600, 648)  = 48 float2 (pair's pooled features)
    float2* c1p2    = wr2;
    float2* pin2    = wr2 + 672;
    float2* c2pT2   = wr2 + 672;
    float2* c3_2    = wr2;
    float2* pooled2 = wr2 + 600;

    float2 sU[4], sV[4];

    const int o0 = lane * 4;
    const float4* fr0 = (const float4*)(fcw + (o0 + 0) * 48);
    const float4* fr1 = (const float4*)(fcw + (o0 + 1) * 48);
    const float4* fr2 = (const float4*)(fcw + (o0 + 2) * 48);
    const float4* fr3 = (const float4*)(fcw + (o0 + 3) * 48);
    const float4 fb = *(const float4*)(fcb + o0);

    #pragma unroll
    for (int pr = 0; pr < 2; ++pr) {
        int sa = base + wv * 4 + pr * 2;
        sa = (sa < B) ? sa : B - 1;
        const int sb = (sa + 1 < B) ? sa + 1 : sa;

        // zero whole scratch: 1664 float2 = 3328 floats
        {
            float4 z4 = {0.f, 0.f, 0.f, 0.f};
            float* w0 = (float*)wr2;
            #pragma unroll
            for (int t = 0; t < 13; ++t)
                *(float4*)(w0 + t * 256 + lane * 4) = z4;
        }
        // interleaved input load: pin2[i] = {xa[i], xb[i]}
        {
            const float4* xsA = (const float4*)(x + (size_t)sa * 784);
            const float4* xsB = (const float4*)(x + (size_t)sb * 784);
            #pragma unroll
            for (int t = 0; t < 4; ++t) {
                int i4 = t * 64 + lane;
                if (i4 < 196) {
                    float4 va = xsA[i4];
                    float4 vb = xsB[i4];
                    int r = i4 / 7;
                    int c = (i4 % 7) * 4;
                    float2* dst = pin2 + (r + 2) * 32 + (c + 2);
                    dst[0] = make_float2(va.x, vb.x);
                    dst[1] = make_float2(va.y, vb.y);
                    dst[2] = make_float2(va.z, vb.z);
                    dst[3] = make_float2(va.w, vb.w);
                }
            }
        }

        // ---- conv1: k5 s2 p2 -> c1p2 [3][14][16] (col+1) ----
        #pragma unroll
        for (int t = 0; t < 4; ++t) {
            int p = t * 64 + lane;
            bool valid = p < 196;
            int pp = valid ? p : 0;
            int y = pp / 14, xx = pp % 14;
            const float2* pr2 = pin2 + (2 * y) * 32 + 2 * xx;
            float2 win[25];
            #pragma unroll
            for (int ky = 0; ky < 5; ++ky) {
                const float2* rw = pr2 + ky * 32;
                #pragma unroll
                for (int j = 0; j < 5; ++j) win[ky * 5 + j] = rw[j];
            }
            #pragma unroll
            for (int c = 0; c < 3; ++c) {
                float ax = c1b[c], ay = c1b[c];
                #pragma unroll
                for (int k = 0; k < 25; ++k) {
                    float wk = c1w[c * 25 + k];
                    ax = fmaf(win[k].x, wk, ax);
                    ay = fmaf(win[k].y, wk, ay);
                }
                if (valid)
                    c1p2[c * 224 + y * 16 + (xx + 1)] =
                        make_float2(fmaxf(ax, 0.f), fmaxf(ay, 0.f));
            }
        }

        // ---- conv2: k3 s2 p1 -> c2pT2 [81][8] (row-masked top row) ----
        {
            float4 z4 = {0.f, 0.f, 0.f, 0.f};
            float4* zz = (float4*)c2pT2;
            #pragma unroll
            for (int t = 0; t < 6; ++t) {
                int i = t * 64 + lane;
                if (i < 324) zz[i] = z4;
            }
        }
        {
            int p = lane;
            bool valid = p < 49;
            int pp = valid ? p : 0;
            int y = pp / 7, xx = pp % 7;
            float acx[6], acy[6];
            #pragma unroll
            for (int c = 0; c < 6; ++c) { acx[c] = c2b[c]; acy[c] = c2b[c]; }
            #pragma unroll
            for (int ic = 0; ic < 3; ++ic) {
                const float2* bic = c1p2 + ic * 224;
                float2 win[9];
                #pragma unroll
                for (int ky = 0; ky < 3; ++ky) {
                    int rr = 2 * y - 1 + ky;
                    bool okr = rr >= 0;
                    int rc = okr ? rr : 0;
                    const float2* rw = bic + rc * 16 + 2 * xx;
                    float2 a0 = rw[0], a1 = rw[1], a2 = rw[2];
                    float2 z2 = {0.f, 0.f};
                    win[ky * 3 + 0] = okr ? a0 : z2;
                    win[ky * 3 + 1] = okr ? a1 : z2;
                    win[ky * 3 + 2] = okr ? a2 : z2;
                }
                #pragma unroll
                for (int c = 0; c < 6; ++c)
                    #pragma unroll
                    for (int k = 0; k < 9; ++k) {
                        float wk = c2w[c * 27 + ic * 9 + k];
                        acx[c] = fmaf(win[k].x, wk, acx[c]);
                        acy[c] = fmaf(win[k].y, wk, acy[c]);
                    }
            }
            if (valid) {
                float2* op = c2pT2 + ((y + 1) * 9 + (xx + 1)) * 8;
                #pragma unroll
                for (int c = 0; c < 6; ++c)
                    op[c] = make_float2(fmaxf(acx[c], 0.f), fmaxf(acy[c], 0.f));
            }
        }

        // ---- conv3: k3 s1 p1 -> c3_2 (over dead c1p2) ----
        {
            int p = lane;
            bool valid = p < 49;
            int pp = valid ? p : 0;
            int y = pp / 7, xx = pp % 7;
            float acx[12], acy[12];
            #pragma unroll
            for (int c = 0; c < 12; ++c) { acx[c] = c3b[c]; acy[c] = c3b[c]; }
            #pragma unroll
            for (int dy = 0; dy < 3; ++dy)
                #pragma unroll
                for (int dx = 0; dx < 3; ++dx) {
                    const float2* cp = c2pT2 + ((y + dy) * 9 + (xx + dx)) * 8;
                    float2 ch[6];
                    #pragma unroll
                    for (int j = 0; j < 6; ++j) ch[j] = cp[j];
                    const int k = dy * 3 + dx;
                    #pragma unroll
                    for (int c = 0; c < 12; ++c) {
                        const float* wp = c3w + c * 54 + k;
                        #pragma unroll
                        for (int j = 0; j < 6; ++j) {
                            float wk = wp[j * 9];
                            acx[c] = fmaf(ch[j].x, wk, acx[c]);
                            acy[c] = fmaf(ch[j].y, wk, acy[c]);
                        }
                    }
                }
            if (valid) {
                #pragma unroll
                for (int c = 0; c < 12; ++c)
                    c3_2[c * 49 + p] = make_float2(fmaxf(acx[c], 0.f), fmaxf(acy[c], 0.f));
            }
        }

        // ---- adaptive pool -> pooled2 (LDS) ----
        {
            int o = lane;
            if (o < 48) {
                int c = o >> 2, i = (o >> 1) & 1, j = o & 1;
                int ri = i * 3, cj = j * 3;
                float sx = 0.f, sy = 0.f;
                #pragma unroll
                for (int dy = 0; dy < 4; ++dy)
                    #pragma unroll
                    for (int dx = 0; dx < 4; ++dx) {
                        float2 v = c3_2[c * 49 + (ri + dy) * 7 + (cj + dx)];
                        sx += v.x; sy += v.y;
                    }
                pooled2[o] = make_float2(sx * (1.f / 16.f), sy * (1.f / 16.f));
            }
        }

        // ---- fc 48->256 + relu + L2-normalize for the pair ----
        {
            float2 a0 = {0.f, 0.f}, a1 = {0.f, 0.f}, a2 = {0.f, 0.f}, a3 = {0.f, 0.f};
            #pragma unroll
            for (int kc = 0; kc < 12; ++kc) {
                float4 w0 = fr0[kc], w1 = fr1[kc], w2 = fr2[kc], w3 = fr3[kc];
                const float2* pv = pooled2 + kc * 4;
                float2 p0 = pv[0], p1 = pv[1], p2 = pv[2], p3 = pv[3];
                a0.x = fmaf(p0.x, w0.x, fmaf(p1.x, w0.y, fmaf(p2.x, w0.z, fmaf(p3.x, w0.w, a0.x))));
                a0.y = fmaf(p0.y, w0.x, fmaf(p1.y, w0.y, fmaf(p2.y, w0.z, fmaf(p3.y, w0.w, a0.y))));
                a1.x = fmaf(p0.x, w1.x, fmaf(p1.x, w1.y, fmaf(p2.x, w1.z, fmaf(p3.x, w1.w, a1.x))));
                a1.y = fmaf(p0.y, w1.x, fmaf(p1.y, w1.y, fmaf(p2.y, w1.z, fmaf(p3.y, w1.w, a1.y))));
                a2.x = fmaf(p0.x, w2.x, fmaf(p1.x, w2.y, fmaf(p2.x, w2.z, fmaf(p3.x, w2.w, a2.x))));
                a2.y = fmaf(p0.y, w2.x, fmaf(p1.y, w2.y, fmaf(p2.y, w2.z, fmaf(p3.y, w2.w, a2.y))));
                a3.x = fmaf(p0.x, w3.x, fmaf(p1.x, w3.y, fmaf(p2.x, w3.z, fmaf(p3.x, w3.w, a3.x))));
                a3.y = fmaf(p0.y, w3.x, fmaf(p1.y, w3.y, fmaf(p2.y, w3.z, fmaf(p3.y, w3.w, a3.y))));
            }
            float2 t0, t1, t2, t3;
            t0.x = fmaxf(a0.x + fb.x, 0.f); t0.y = fmaxf(a0.y + fb.x, 0.f);
            t1.x = fmaxf(a1.x + fb.y, 0.f); t1.y = fmaxf(a1.y + fb.y, 0.f);
            t2.x = fmaxf(a2.x + fb.z, 0.f); t2.y = fmaxf(a2.y + fb.z, 0.f);
            t3.x = fmaxf(a3.x + fb.w, 0.f); t3.y = fmaxf(a3.y + fb.w, 0.f);
            float ssx = fmaf(t0.x, t0.x, fmaf(t1.x, t1.x, fmaf(t2.x, t2.x, t3.x * t3.x)));
            float ssy = fmaf(t0.y, t0.y, fmaf(t1.y, t1.y, fmaf(t2.y, t2.y, t3.y * t3.y)));
            #pragma unroll
            for (int m = 1; m < 64; m <<= 1) {
                ssx += __shfl_xor(ssx, m);
                ssy += __shfl_xor(ssy, m);
            }
            float scx = 1.f / fmaxf(sqrtf(ssx), 1e-12f);
            float scy = 1.f / fmaxf(sqrtf(ssy), 1e-12f);
            t0.x *= scx; t1.x *= scx; t2.x *= scx; t3.x *= scx;
            t0.y *= scy; t1.y *= scy; t2.y *= scy; t3.y *= scy;
            if (pr == 0) { sU[0] = t0; sU[1] = t1; sU[2] = t2; sU[3] = t3; }
            else         { sV[0] = t0; sV[1] = t1; sV[2] = t2; sV[3] = t3; }
        }
    }

    // ---- qsim: 56 conjugated rotations on 2 packed chain-pairs (4 samples) ----
    ROTLAYER2(0) ROTLAYER2(1) ROTLAYER2(2) ROTLAYER2(3)
    ROTLAYER2(4) ROTLAYER2(5) ROTLAYER2(6)

    // ---- measurement: bit7 = lane bit5 ----
    float2 pU, pV;
    pU.x = sU[0].x*sU[0].x + sU[1].x*sU[1].x + sU[2].x*sU[2].x + sU[3].x*sU[3].x;
    pU.y = sU[0].y*sU[0].y + sU[1].y*sU[1].y + sU[2].y*sU[2].y + sU[3].y*sU[3].y;
    pV.x = sV[0].x*sV[0].x + sV[1].x*sV[1].x + sV[2].x*sV[2].x + sV[3].x*sV[3].x;
    pV.y = sV[0].y*sV[0].y + sV[1].y*sV[1].y + sV[2].y*sV[2].y + sV[3].y*sV[3].y;
    if (lane & 32) { pU.x = -pU.x; pU.y = -pU.y; pV.x = -pV.x; pV.y = -pV.y; }
    #pragma unroll
    for (int m = 1; m < 64; m <<= 1) {
        pU.x += __shfl_xor(pU.x, m); pU.y += __shfl_xor(pU.y, m);
        pV.x += __shfl_xor(pV.x, m); pV.y += __shfl_xor(pV.y, m);
    }

    if (lane < 4) {
        float qout = (lane == 0) ? pU.x : (lane == 1) ? pU.y : (lane == 2) ? pV.x : pV.y;
        int osample = base + wv * 4 + lane;
        float u = (qout + 1.f) * 0.5f * (float)(NL - 1);
        int i0 = (int)floorf(u);
        i0 = (i0 < 0) ? 0 : ((i0 > NL - 2) ? NL - 2 : i0);
        float fr = u - (float)i0;
        float z0 = lut[i0], z1 = lut[i0 + 1];
        float z = fmaf(z1 - z0, fr, z0);
        if (osample < B) out[osample] = 1.f / (1.f + expf(-z));
    }
}

extern "C" void kernel_launch(void* const* d_in, const int* in_sizes, int n_in,
                              void* d_out, int out_size, void* d_ws, size_t ws_size,
                              hipStream_t stream) {
    const float* x   = (const float*)d_in[0];
    const float* c1w = (const float*)d_in[1];
    const float* c1b = (const float*)d_in[2];
    const float* c2w = (const float*)d_in[3];
    const float* c2b = (const float*)d_in[4];
    const float* c3w = (const float*)d_in[5];
    const float* c3b = (const float*)d_in[6];
    const float* fcw = (const float*)d_in[7];
    const float* fcb = (const float*)d_in[8];
    const float* qw  = (const float*)d_in[9];
    const float* w1  = (const float*)d_in[10];
    const float* b1  = (const float*)d_in[11];
    const float* w2  = (const float*)d_in[12];
    const float* b2  = (const float*)d_in[13];
    const float* w3  = (const float*)d_in[14];
    const float* b3  = (const float*)d_in[15];
    const float* w4  = (const float*)d_in[16];
    const float* b4  = (const float*)d_in[17];
    const float* w5  = (const float*)d_in[18];
    const float* b5  = (const float*)d_in[19];

    float* lut = (float*)d_ws;   // [0,NL): z; [NL,NL+112): cos/sin

    int B = in_sizes[0] / 784;

    build_lut<<<dim3(NL / 16), dim3(256), 0, stream>>>(
        w1, b1, w2, b2, w3, b3, w4, b4, w5, b5, qw, lut);

    int grid = (B + 15) / 16;
    fused_all<<<dim3(grid), dim3(256), 0, stream>>>(
        x, c1w, c1b, c2w, c2b, c3w, c3b, fcw, fcb, lut,
        (float*)d_out, B);
}